// Round 7
// baseline (1347.019 us; speedup 1.0000x reference)
//
#include <hip/hip_runtime.h>
#include <hip/hip_bf16.h>
#include <math.h>

#define GAMMA_ 0.99f
#define EPS_ 1e-8f

typedef __attribute__((ext_vector_type(8))) short s16x8;
typedef __attribute__((ext_vector_type(4))) float f32x4;

__device__ __forceinline__ unsigned short f2bf(float f){
  unsigned u = __float_as_uint(f);
  unsigned r = (u + 0x7FFFu + ((u >> 16) & 1u)) >> 16;
  return (unsigned short)r;
}
__device__ __forceinline__ float bf2f(unsigned short h){
  return __uint_as_float(((unsigned)h) << 16);
}

__device__ __forceinline__ float2 cmul(float2 a, float2 b){
  return make_float2(a.x*b.x - a.y*b.y, a.x*b.y + a.y*b.x);
}
__device__ __forceinline__ float2 cadd(float2 a, float2 b){ return make_float2(a.x+b.x, a.y+b.y); }
__device__ __forceinline__ float2 csub(float2 a, float2 b){ return make_float2(a.x-b.x, a.y-b.y); }

// ---------------- FFT (4096-pt complex, 256 threads, LDS-resident) ----------------
__device__ void fft_dif(float2* z, const float2* tw, int tid){
  for (int s = 0; s < 12; ++s){
    __syncthreads();
    int half = 2048 >> s;
    for (int b = tid; b < 2048; b += 256){
      int j  = b & (half - 1);
      int g  = b >> (11 - s);
      int i0 = (g << (12 - s)) + j;
      int i1 = i0 + half;
      float2 u = z[i0], v = z[i1];
      z[i0] = cadd(u, v);
      z[i1] = cmul(csub(u, v), tw[j << s]);
    }
  }
  __syncthreads();
}
__device__ void fft_dit(float2* z, const float2* tw, int tid){
  for (int s = 0; s < 12; ++s){
    __syncthreads();
    int half = 1 << s;
    for (int b = tid; b < 2048; b += 256){
      int j  = b & (half - 1);
      int g  = b >> s;
      int i0 = (g << (s + 1)) + j;
      int i1 = i0 + half;
      float2 u = z[i0];
      float2 t = cmul(z[i1], tw[j << (11 - s)]);
      z[i0] = cadd(u, t);
      z[i1] = csub(u, t);
    }
  }
  __syncthreads();
}
__device__ __forceinline__ void tw_init(float2* tw, int tid){
  for (int j = tid; j < 2048; j += 256){
    float th = -(float)(3.14159265358979323846 / 2048.0) * (float)j;
    float s_, c_; __sincosf(th, &s_, &c_);
    tw[j] = make_float2(c_, s_);
  }
}
__device__ __forceinline__ int rev12(int x){ return (int)(__brev((unsigned)x) >> 20); }

// ---------------- transpose + split prep kernel ----------------
// W [K][N] fp32 -> Th/Tl [N][K] bf16 (tiled transpose + split)
__global__ __launch_bounds__(256)
void transpose_split(const float* __restrict__ W, ushort* __restrict__ Th,
                     ushort* __restrict__ Tl, int K, int N){
  __shared__ float T[32][33];
  int n0 = blockIdx.x * 32, k0 = blockIdx.y * 32;
  int tid = threadIdx.x;
  int j = tid & 31, i = tid >> 5;         // i in 0..7
#pragma unroll
  for (int p = 0; p < 4; ++p)
    T[i + 8*p][j] = W[(size_t)(k0 + i + 8*p) * N + n0 + j];
  __syncthreads();
#pragma unroll
  for (int p = 0; p < 4; ++p){
    int r = i + 8*p;                      // output row n0+r, col k0+j
    float f = T[j][r];
    unsigned short hh = f2bf(f);
    Th[(size_t)(n0 + r) * K + k0 + j] = hh;
    Tl[(size_t)(n0 + r) * K + k0 + j] = f2bf(f - bf2f(hh));
  }
}

// ---------------- split-bf16 MFMA GEMM ----------------
// C = act(A @ B^T + bias), B=[N][K] bf16 pair.
// ASRC 0: A = bf16 hi/lo pair [M][K] (Ah/Al).  ASRC 1: A = fp32 [M][K] (Af),
//         split to hi/lo in registers during staging.
// OUTMODE 0: fp32 row-major [M][N]
// OUTMODE 1: fp32 channel-major C[((row>>11)*N + col)*2048 + (row&2047)]
// OUTMODE 2: bf16 hi/lo pair row-major [M][N]
template<int ACT, int OUTMODE, int ASRC>
__global__ __launch_bounds__(256)
void gemm_mfma(const float* __restrict__ Af,
               const ushort* __restrict__ Ah, const ushort* __restrict__ Al,
               const ushort* __restrict__ Bh, const ushort* __restrict__ Bl,
               const float* __restrict__ bias,
               float* __restrict__ C, ushort* __restrict__ Ch, ushort* __restrict__ Cl,
               int M, int N, int K)
{
  __shared__ ushort Ash[128][40];
  __shared__ ushort Asl[128][40];
  __shared__ ushort Bsh[128][40];
  __shared__ ushort Bsl[128][40];
  int tid = threadIdx.x;
  // XCD-aware bijective swizzle (nwg % 8 == 0 for all our launches)
  int gx = gridDim.x;
  int nwg = gx * gridDim.y;
  int flat = blockIdx.y * gx + blockIdx.x;
  int s = (flat & 7) * (nwg >> 3) + (flat >> 3);
  int bx = s % gx, by = s / gx;
  int row0 = by * 128, col0 = bx * 128;
  int w = tid >> 6, lane = tid & 63;
  int wm = w >> 1, wn = w & 1;
  int lr = lane & 15, lg = lane >> 4;
  f32x4 acc[4][4] = {};

  for (int k0 = 0; k0 < K; k0 += 32){
    __syncthreads();
#pragma unroll
    for (int p = 0; p < 2; ++p){
      int c = tid + (p << 8);
      int r = c >> 2, kk = (c & 3) << 3;
      if (ASRC == 0){
        *(uint4*)&Ash[r][kk] = *(const uint4*)&Ah[(size_t)(row0 + r) * K + k0 + kk];
        *(uint4*)&Asl[r][kk] = *(const uint4*)&Al[(size_t)(row0 + r) * K + k0 + kk];
      } else {
        const float* src = &Af[(size_t)(row0 + r) * K + k0 + kk];
        float4 f0 = *(const float4*)src;
        float4 f1 = *(const float4*)(src + 4);
        float fs[8] = {f0.x, f0.y, f0.z, f0.w, f1.x, f1.y, f1.z, f1.w};
        uint hv[4], lv[4];
#pragma unroll
        for (int q = 0; q < 4; ++q){
          unsigned short h0 = f2bf(fs[2*q]),     h1 = f2bf(fs[2*q+1]);
          unsigned short l0 = f2bf(fs[2*q]   - bf2f(h0));
          unsigned short l1 = f2bf(fs[2*q+1] - bf2f(h1));
          hv[q] = (uint)h0 | ((uint)h1 << 16);
          lv[q] = (uint)l0 | ((uint)l1 << 16);
        }
        *(uint4*)&Ash[r][kk] = make_uint4(hv[0], hv[1], hv[2], hv[3]);
        *(uint4*)&Asl[r][kk] = make_uint4(lv[0], lv[1], lv[2], lv[3]);
      }
      *(uint4*)&Bsh[r][kk] = *(const uint4*)&Bh[(size_t)(col0 + r) * K + k0 + kk];
      *(uint4*)&Bsl[r][kk] = *(const uint4*)&Bl[(size_t)(col0 + r) * K + k0 + kk];
    }
    __syncthreads();
    s16x8 ah[4], al[4], bh[4], bl[4];
#pragma unroll
    for (int m = 0; m < 4; ++m){
      ah[m] = *(const s16x8*)&Ash[wm*64 + m*16 + lr][lg*8];
      al[m] = *(const s16x8*)&Asl[wm*64 + m*16 + lr][lg*8];
    }
#pragma unroll
    for (int n = 0; n < 4; ++n){
      bh[n] = *(const s16x8*)&Bsh[wn*64 + n*16 + lr][lg*8];
      bl[n] = *(const s16x8*)&Bsl[wn*64 + n*16 + lr][lg*8];
    }
#pragma unroll
    for (int m = 0; m < 4; ++m)
#pragma unroll
      for (int n = 0; n < 4; ++n){
        acc[m][n] = __builtin_amdgcn_mfma_f32_16x16x32_bf16(ah[m], bh[n], acc[m][n], 0, 0, 0);
        acc[m][n] = __builtin_amdgcn_mfma_f32_16x16x32_bf16(ah[m], bl[n], acc[m][n], 0, 0, 0);
        acc[m][n] = __builtin_amdgcn_mfma_f32_16x16x32_bf16(al[m], bh[n], acc[m][n], 0, 0, 0);
      }
  }

#pragma unroll
  for (int m = 0; m < 4; ++m){
    int grow_base = row0 + wm*64 + m*16 + lg*4;
#pragma unroll
    for (int n = 0; n < 4; ++n){
      int gcol = col0 + wn*64 + n*16 + lr;
      float bv = bias[gcol];
      if (OUTMODE == 1){
        float4 o; float* op = (float*)&o;
#pragma unroll
        for (int r = 0; r < 4; ++r){
          float v2 = acc[m][n][r] + bv;
          if (ACT) v2 = v2 / (1.f + __expf(-v2));
          op[r] = v2;
        }
        int bb = grow_base >> 11, t = grow_base & 2047;
        *(float4*)&C[((size_t)bb * N + gcol) * 2048 + t] = o;
      } else {
#pragma unroll
        for (int r = 0; r < 4; ++r){
          float v2 = acc[m][n][r] + bv;
          if (ACT) v2 = v2 / (1.f + __expf(-v2));
          int grow = grow_base + r;
          if (OUTMODE == 0){
            C[(size_t)grow * N + gcol] = v2;
          } else {
            unsigned short hh = f2bf(v2);
            Ch[(size_t)grow * N + gcol] = hh;
            Cl[(size_t)grow * N + gcol] = f2bf(v2 - bf2f(hh));
          }
        }
      }
    }
  }
}

// ---------------- small kernels ----------------
__global__ __launch_bounds__(256)
void pos_init(const float* __restrict__ pw, const float* __restrict__ pb, float* __restrict__ h){
  int idx = blockIdx.x * 256 + threadIdx.x;
  int t = idx >> 9, r = idx & 511;
  h[idx] = (float)t * pw[r] + pb[r];
}

// srms + relu + bf16 hi/lo split (feeds MFMA pos-MLP GEMMs)
__global__ __launch_bounds__(256)
void srms_relu_split(const float* __restrict__ in, ushort* __restrict__ oh,
                     ushort* __restrict__ ol){
  __shared__ float red[256];
  int row = blockIdx.x, tid = threadIdx.x;
  const float* r = in + (size_t)row * 512;
  float a = r[tid], b = r[tid + 256];
  red[tid] = a*a + b*b;
  __syncthreads();
  for (int off = 128; off > 0; off >>= 1){
    if (tid < off) red[tid] += red[tid + off];
    __syncthreads();
  }
  float rms = sqrtf(red[0] * (1.f / 512.f));
  float inv = 1.f / (rms + EPS_);
  size_t base = (size_t)row * 512;
  float va = a * inv; va = va > 0.f ? va : 0.f;
  float vb = b * inv; vb = vb > 0.f ? vb : 0.f;
  unsigned short ha = f2bf(va), hb = f2bf(vb);
  oh[base + tid]       = ha; ol[base + tid]       = f2bf(va - bf2f(ha));
  oh[base + tid + 256] = hb; ol[base + tid + 256] = f2bf(vb - bf2f(hb));
}

// Build A-spectra for pairs [pbase, pbase+gridDim.x): channels (2p,2p+1)
__global__ __launch_bounds__(256)
void build_aspec(const float* __restrict__ coefs_t, float2* __restrict__ aspec, int pbase){
  __shared__ float2 z[4096];
  __shared__ float2 tw[2048];
  int tid = threadIdx.x, slot = blockIdx.x, p = pbase + slot;
  tw_init(tw, tid);
  const float* c0 = coefs_t + (size_t)(2*p) * 2048;
  const float* c1 = c0 + 2048;
  const float l2g = log2f(GAMMA_);
  for (int t = tid; t < 2048; t += 256){
    float g = exp2f(l2g * (float)t);
    z[t] = make_float2(c0[t] * g, c1[t] * g);
  }
  for (int t = 2048 + tid; t < 4096; t += 256) z[t] = make_float2(0.f, 0.f);
  fft_dif(z, tw, tid);
  for (int k = tid; k <= 2048; k += 256){
    float2 zk = z[rev12(k)];
    float2 zm = z[rev12((4096 - k) & 4095)];
    float2 A0 = make_float2(0.5f*(zk.x + zm.x),  0.5f*(zk.y - zm.y));
    float2 A1 = make_float2(0.5f*(zk.y + zm.y), -0.5f*(zk.x - zm.x));
    *(float4*)(aspec + ((size_t)slot * 2049 + k) * 2) = make_float4(A0.x, A0.y, A1.x, A1.y);
  }
}

// Conv for pairs [pbase, pbase+gridDim.x): FFT, pointwise, inverse; in-place on vt
__global__ __launch_bounds__(256)
void conv_fft(float* __restrict__ vt, const float4* __restrict__ aspec, int pbase){
  __shared__ float2 z[4096];
  __shared__ float2 tw[2048];
  int tid = threadIdx.x, slot = blockIdx.x, p = pbase + slot, bb = blockIdx.y;
  tw_init(tw, tid);
  float* v0 = vt + ((size_t)bb * 3072 + 2*p) * 2048;
  float* v1 = v0 + 2048;
  for (int t = tid; t < 2048; t += 256) z[t] = make_float2(v0[t], v1[t]);
  for (int t = 2048 + tid; t < 4096; t += 256) z[t] = make_float2(0.f, 0.f);
  fft_dif(z, tw, tid);
  for (int k = tid; k <= 2048; k += 256){
    int rk  = rev12(k);
    int rmk = rev12((4096 - k) & 4095);
    float2 zk = z[rk], zm = z[rmk];
    float2 V0 = make_float2(0.5f*(zk.x + zm.x),  0.5f*(zk.y - zm.y));
    float2 V1 = make_float2(0.5f*(zk.y + zm.y), -0.5f*(zk.x - zm.x));
    float4 av = aspec[(size_t)slot * 2049 + k];
    float2 P0 = cmul(V0, make_float2(av.x, av.y));
    float2 P1 = cmul(V1, make_float2(av.z, av.w));
    z[rk]  = make_float2(P0.x - P1.y, -(P0.y + P1.x));
    z[rmk] = make_float2(P0.x + P1.y,   P0.y - P1.x);
  }
  fft_dit(z, tw, tid);
  const float sc = 1.f / 4096.f;
  for (int t = tid; t < 2048; t += 256){
    float2 w = z[t];
    v0[t] =  w.x * sc;
    v1[t] = -w.y * sc;
  }
}

// P = u .* tv written IN PLACE over u (hi/lo). Each element read+written by the
// same thread, so aliasing is race-free. No __restrict__ on uh/ul.
__global__ __launch_bounds__(256)
void fuse_mul_inplace(ushort* uh, ushort* ul, const float* __restrict__ vt){
  __shared__ float T[64][65];
  int tid = threadIdx.x;
  int c0 = blockIdx.x * 64, t0 = blockIdx.y * 64;
  size_t b = blockIdx.z;
  {
    int j = tid >> 2, q = tid & 3;
    const float* src = vt + ((b * 3072 + c0 + j) * 2048 + t0 + q * 16);
#pragma unroll
    for (int f = 0; f < 4; ++f){
      float4 v = *(const float4*)(src + f * 4);
      T[j][q*16 + f*4 + 0] = v.x;
      T[j][q*16 + f*4 + 1] = v.y;
      T[j][q*16 + f*4 + 2] = v.z;
      T[j][q*16 + f*4 + 3] = v.w;
    }
  }
  __syncthreads();
  int i = tid >> 2, q = tid & 3;
  size_t orow = b * 2048 + t0 + i;
#pragma unroll
  for (int f = 0; f < 4; ++f){
    int jc = q*16 + f*4;
    ushort4 hv = *(const ushort4*)&uh[orow * 3072 + c0 + jc];
    ushort4 lv = *(const ushort4*)&ul[orow * 3072 + c0 + jc];
    ushort4 oh, ol;
    float uu, pp; unsigned short hh;
    uu = bf2f(hv.x) + bf2f(lv.x); pp = uu * T[jc+0][i];
    hh = f2bf(pp); oh.x = hh; ol.x = f2bf(pp - bf2f(hh));
    uu = bf2f(hv.y) + bf2f(lv.y); pp = uu * T[jc+1][i];
    hh = f2bf(pp); oh.y = hh; ol.y = f2bf(pp - bf2f(hh));
    uu = bf2f(hv.z) + bf2f(lv.z); pp = uu * T[jc+2][i];
    hh = f2bf(pp); oh.z = hh; ol.z = f2bf(pp - bf2f(hh));
    uu = bf2f(hv.w) + bf2f(lv.w); pp = uu * T[jc+3][i];
    hh = f2bf(pp); oh.w = hh; ol.w = f2bf(pp - bf2f(hh));
    *(ushort4*)&uh[orow * 3072 + c0 + jc] = oh;
    *(ushort4*)&ul[orow * 3072 + c0 + jc] = ol;
  }
}

extern "C" void kernel_launch(void* const* d_in, const int* in_sizes, int n_in,
                              void* d_out, int out_size, void* d_ws, size_t ws_size,
                              hipStream_t stream)
{
  const float* x     = (const float*)d_in[0];
  const float* u_w   = (const float*)d_in[1];
  const float* u_b   = (const float*)d_in[2];
  const float* v_w   = (const float*)d_in[3];
  const float* v_b   = (const float*)d_in[4];
  const float* o_w   = (const float*)d_in[5];
  const float* o_b   = (const float*)d_in[6];
  const float* pos_w = (const float*)d_in[7];
  const float* pos_b = (const float*)d_in[8];
  const float* lw0   = (const float*)d_in[9];
  const float* lb0   = (const float*)d_in[10];
  const float* lw1   = (const float*)d_in[11];
  const float* lb1   = (const float*)d_in[12];
  const float* lw2   = (const float*)d_in[13];
  const float* lb2   = (const float*)d_in[14];
  const float* out_w = (const float*)d_in[15];
  const float* out_b = (const float*)d_in[16];
  float* out = (float*)d_out;

  // Footprint: 201,326,592 persistent + 17,825,792 alias = 219,152,384 B (209 MiB).
  // coefs_t lives in d_out (25.2 MB of 33.5 MB; final GEMM overwrites all of d_out).
  // Diagnostic guard: too-small ws -> clean wrong-answer (poison stays), not a crash.
  if (ws_size < 219152384) return;

  char* ws = (char*)d_ws;
  // ---- persistent region (201,326,592 B) ----
  ushort* uhi  = (ushort*)(ws);                    // 50,331,648  (u, later P hi)
  ushort* ulo  = (ushort*)(ws + 50331648);         // 50,331,648  (u, later P lo)
  float*  vt   = (float*) (ws + 100663296);        // 100,663,296 (v, later tv)
  // ---- alias region R (extent 17,825,792 B) ----
  char* R = ws + 201326592;
  // phase A (u/v GEMMs): weight-transpose slot, serialized u_w then v_w
  ushort* wT_h   = (ushort*)(R);                   // 6,291,456
  ushort* wT_l   = (ushort*)(R + 6291456);         // 6,291,456  -> end 12,582,912
  // phase B (pos-MLP; starts after v-GEMM):
  ushort* hb_h   = (ushort*)(R);                   // 2,097,152
  ushort* hb_l   = (ushort*)(R + 2097152);         // 2,097,152
  ushort* owtT_h = (ushort*)(R + 4194304);         // 3,145,728  (out_w^T hi)
  ushort* owtT_l = (ushort*)(R + 7340032);         // 3,145,728  -> end 10,485,760
  float*  h_a    = (float*) (R + 10485760);        // 4,194,304  -> end 14,680,064
  ushort* lw0T_h = (ushort*)(R + 14680064);        // 524,288 each
  ushort* lw0T_l = (ushort*)(R + 15204352);
  ushort* lw1T_h = (ushort*)(R + 15728640);
  ushort* lw1T_l = (ushort*)(R + 16252928);
  ushort* lw2T_h = (ushort*)(R + 16777216);
  ushort* lw2T_l = (ushort*)(R + 17301504);        // -> end 17,825,792
  float*  coefs_t= (float*)d_out;                  // 25,165,824 in d_out (33.5 MB)
  // phase B2 (spectra passes; hb/owtT dead): 256 pairs/pass
  float2* aspec  = (float2*)(R);                   // 8,392,704 per pass
  // phase C (after conv done; aspec dead): o_w^T for the final GEMM
  ushort* owT_h  = (ushort*)(R);                   // 6,291,456
  ushort* owT_l  = (ushort*)(R + 6291456);         // 6,291,456

  dim3 blk(256);
  // ---- phase A: u/v GEMMs read x fp32 directly (ASRC=1, on-the-fly split) ----
  transpose_split<<<dim3(96, 32), blk, 0, stream>>>(u_w, wT_h, wT_l, 1024, 3072);
  gemm_mfma<1,2,1><<<dim3(24, 64), blk, 0, stream>>>(x, nullptr, nullptr, wT_h, wT_l, u_b,
                                                     nullptr, uhi, ulo, 8192, 3072, 1024);
  transpose_split<<<dim3(96, 32), blk, 0, stream>>>(v_w, wT_h, wT_l, 1024, 3072);
  gemm_mfma<1,1,1><<<dim3(24, 64), blk, 0, stream>>>(x, nullptr, nullptr, wT_h, wT_l, v_b,
                                                     vt, nullptr, nullptr, 8192, 3072, 1024);
  // ---- phase B: position MLP (split-bf16 MFMA); coefs land in d_out ----
  pos_init<<<4096, blk, 0, stream>>>(pos_w, pos_b, h_a);
  transpose_split<<<dim3(16, 16), blk, 0, stream>>>(lw0, lw0T_h, lw0T_l, 512, 512);
  transpose_split<<<dim3(16, 16), blk, 0, stream>>>(lw1, lw1T_h, lw1T_l, 512, 512);
  transpose_split<<<dim3(16, 16), blk, 0, stream>>>(lw2, lw2T_h, lw2T_l, 512, 512);
  transpose_split<<<dim3(96, 16), blk, 0, stream>>>(out_w, owtT_h, owtT_l, 512, 3072);
  srms_relu_split<<<2048, blk, 0, stream>>>(h_a, hb_h, hb_l);
  gemm_mfma<0,0,0><<<dim3(4, 16), blk, 0, stream>>>(nullptr, hb_h, hb_l, lw0T_h, lw0T_l, lb0,
                                                    h_a, nullptr, nullptr, 2048, 512, 512);
  srms_relu_split<<<2048, blk, 0, stream>>>(h_a, hb_h, hb_l);
  gemm_mfma<0,0,0><<<dim3(4, 16), blk, 0, stream>>>(nullptr, hb_h, hb_l, lw1T_h, lw1T_l, lb1,
                                                    h_a, nullptr, nullptr, 2048, 512, 512);
  srms_relu_split<<<2048, blk, 0, stream>>>(h_a, hb_h, hb_l);
  gemm_mfma<0,0,0><<<dim3(4, 16), blk, 0, stream>>>(nullptr, hb_h, hb_l, lw2T_h, lw2T_l, lb2,
                                                    h_a, nullptr, nullptr, 2048, 512, 512);
  srms_relu_split<<<2048, blk, 0, stream>>>(h_a, hb_h, hb_l);
  // coefs_t[c][t] via OUTMODE 1 (M=2048 -> bb=0); written into d_out scratch
  gemm_mfma<0,1,0><<<dim3(24, 16), blk, 0, stream>>>(nullptr, hb_h, hb_l, owtT_h, owtT_l, out_b,
                                                     coefs_t, nullptr, nullptr, 2048, 3072, 512);
  // ---- FFT convolution: 6 passes of 256 channel pairs (aspec buffer reused) ----
  for (int pass = 0; pass < 6; ++pass){
    build_aspec<<<256, blk, 0, stream>>>(coefs_t, aspec, pass * 256);
    conv_fft<<<dim3(256, 4), blk, 0, stream>>>(vt, (const float4*)aspec, pass * 256);
  }
  // ---- phase C: o_w^T, then P = u .* tv in place, then out = P @ o_w + o_b ----
  transpose_split<<<dim3(32, 96), blk, 0, stream>>>(o_w, owT_h, owT_l, 3072, 1024);
  fuse_mul_inplace<<<dim3(48, 32, 4), blk, 0, stream>>>(uhi, ulo, vt);
  gemm_mfma<0,0,0><<<dim3(8, 64), blk, 0, stream>>>(nullptr, uhi, ulo, owT_h, owT_l, o_b,
                                                    out, nullptr, nullptr, 8192, 1024, 3072);
}

// Round 8
// 1302.889 us; speedup vs baseline: 1.0339x; 1.0339x over previous
//
#include <hip/hip_runtime.h>
#include <hip/hip_bf16.h>
#include <math.h>

#define GAMMA_ 0.99f
#define EPS_ 1e-8f

typedef __attribute__((ext_vector_type(8))) short s16x8;
typedef __attribute__((ext_vector_type(4))) float f32x4;

__device__ __forceinline__ unsigned short f2bf(float f){
  unsigned u = __float_as_uint(f);
  unsigned r = (u + 0x7FFFu + ((u >> 16) & 1u)) >> 16;
  return (unsigned short)r;
}
__device__ __forceinline__ float bf2f(unsigned short h){
  return __uint_as_float(((unsigned)h) << 16);
}

__device__ __forceinline__ float2 cmul(float2 a, float2 b){
  return make_float2(a.x*b.x - a.y*b.y, a.x*b.y + a.y*b.x);
}
__device__ __forceinline__ float2 cadd(float2 a, float2 b){ return make_float2(a.x+b.x, a.y+b.y); }
__device__ __forceinline__ float2 csub(float2 a, float2 b){ return make_float2(a.x-b.x, a.y-b.y); }

// ---------------- FFT (4096-pt complex, 256 threads, LDS-resident) ----------------
__device__ void fft_dif(float2* z, const float2* tw, int tid){
  for (int s = 0; s < 12; ++s){
    __syncthreads();
    int half = 2048 >> s;
    for (int b = tid; b < 2048; b += 256){
      int j  = b & (half - 1);
      int g  = b >> (11 - s);
      int i0 = (g << (12 - s)) + j;
      int i1 = i0 + half;
      float2 u = z[i0], v = z[i1];
      z[i0] = cadd(u, v);
      z[i1] = cmul(csub(u, v), tw[j << s]);
    }
  }
  __syncthreads();
}
__device__ void fft_dit(float2* z, const float2* tw, int tid){
  for (int s = 0; s < 12; ++s){
    __syncthreads();
    int half = 1 << s;
    for (int b = tid; b < 2048; b += 256){
      int j  = b & (half - 1);
      int g  = b >> s;
      int i0 = (g << (s + 1)) + j;
      int i1 = i0 + half;
      float2 u = z[i0];
      float2 t = cmul(z[i1], tw[j << (11 - s)]);
      z[i0] = cadd(u, t);
      z[i1] = csub(u, t);
    }
  }
  __syncthreads();
}
__device__ __forceinline__ void tw_init(float2* tw, int tid){
  for (int j = tid; j < 2048; j += 256){
    float th = -(float)(3.14159265358979323846 / 2048.0) * (float)j;
    float s_, c_; __sincosf(th, &s_, &c_);
    tw[j] = make_float2(c_, s_);
  }
}
__device__ __forceinline__ int rev12(int x){ return (int)(__brev((unsigned)x) >> 20); }

// ---------------- transpose + split prep kernel ----------------
// W [K][N] fp32 -> Th/Tl [N][K] bf16 (tiled transpose + split)
__global__ __launch_bounds__(256)
void transpose_split(const float* __restrict__ W, ushort* __restrict__ Th,
                     ushort* __restrict__ Tl, int K, int N){
  __shared__ float T[32][33];
  int n0 = blockIdx.x * 32, k0 = blockIdx.y * 32;
  int tid = threadIdx.x;
  int j = tid & 31, i = tid >> 5;         // i in 0..7
#pragma unroll
  for (int p = 0; p < 4; ++p)
    T[i + 8*p][j] = W[(size_t)(k0 + i + 8*p) * N + n0 + j];
  __syncthreads();
#pragma unroll
  for (int p = 0; p < 4; ++p){
    int r = i + 8*p;                      // output row n0+r, col k0+j
    float f = T[j][r];
    unsigned short hh = f2bf(f);
    Th[(size_t)(n0 + r) * K + k0 + j] = hh;
    Tl[(size_t)(n0 + r) * K + k0 + j] = f2bf(f - bf2f(hh));
  }
}

// ---------------- split-bf16 MFMA GEMM ----------------
// C = act(A @ B^T + bias), B=[N][K] bf16 pair.
// ASRC 0: A = bf16 hi/lo pair [M][K] (Ah/Al).  ASRC 1: A = fp32 [M][K] (Af),
//         split to hi/lo in registers during staging.
// OUTMODE 0: fp32 row-major [M][N]
// OUTMODE 1: fp32 channel-major C[((row>>11)*N + col)*2048 + (row&2047)]
// OUTMODE 2: bf16 hi/lo pair row-major [M][N]
//
// LDS: unpadded [128][32] ushort (64B rows) with 16B-chunk XOR swizzle
//   physical_chunk = logical_chunk ^ ((row>>1)&3)
// Bank-quad = 4*(row&1) + physical_chunk (mod 8): any 8 consecutive lanes of
// the b128 read (shared lg, 8 consecutive rows) hit all 8 quads exactly once
// -> conflict-free; write side (2 rows x 4 chunks per 8 lanes) likewise.
template<int ACT, int OUTMODE, int ASRC>
__global__ __launch_bounds__(256)
void gemm_mfma(const float* __restrict__ Af,
               const ushort* __restrict__ Ah, const ushort* __restrict__ Al,
               const ushort* __restrict__ Bh, const ushort* __restrict__ Bl,
               const float* __restrict__ bias,
               float* __restrict__ C, ushort* __restrict__ Ch, ushort* __restrict__ Cl,
               int M, int N, int K)
{
  __shared__ ushort Ash[128*32];
  __shared__ ushort Asl[128*32];
  __shared__ ushort Bsh[128*32];
  __shared__ ushort Bsl[128*32];
  int tid = threadIdx.x;
  // XCD-aware bijective swizzle (nwg % 8 == 0 for all our launches)
  int gx = gridDim.x;
  int nwg = gx * gridDim.y;
  int flat = blockIdx.y * gx + blockIdx.x;
  int s = (flat & 7) * (nwg >> 3) + (flat >> 3);
  int bx = s % gx, by = s / gx;
  int row0 = by * 128, col0 = bx * 128;
  int w = tid >> 6, lane = tid & 63;
  int wm = w >> 1, wn = w & 1;
  int lr = lane & 15, lg = lane >> 4;
  f32x4 acc[4][4] = {};

  for (int k0 = 0; k0 < K; k0 += 32){
    __syncthreads();
#pragma unroll
    for (int p = 0; p < 2; ++p){
      int c = tid + (p << 8);
      int r = c >> 2, ch = c & 3;
      int kk = ch << 3;                                   // source k-offset (ushorts)
      int off = (r << 5) + ((ch ^ ((r >> 1) & 3)) << 3);  // swizzled LDS offset
      if (ASRC == 0){
        *(uint4*)&Ash[off] = *(const uint4*)&Ah[(size_t)(row0 + r) * K + k0 + kk];
        *(uint4*)&Asl[off] = *(const uint4*)&Al[(size_t)(row0 + r) * K + k0 + kk];
      } else {
        const float* src = &Af[(size_t)(row0 + r) * K + k0 + kk];
        float4 f0 = *(const float4*)src;
        float4 f1 = *(const float4*)(src + 4);
        float fs[8] = {f0.x, f0.y, f0.z, f0.w, f1.x, f1.y, f1.z, f1.w};
        uint hv[4], lv[4];
#pragma unroll
        for (int q = 0; q < 4; ++q){
          unsigned short h0 = f2bf(fs[2*q]),     h1 = f2bf(fs[2*q+1]);
          unsigned short l0 = f2bf(fs[2*q]   - bf2f(h0));
          unsigned short l1 = f2bf(fs[2*q+1] - bf2f(h1));
          hv[q] = (uint)h0 | ((uint)h1 << 16);
          lv[q] = (uint)l0 | ((uint)l1 << 16);
        }
        *(uint4*)&Ash[off] = make_uint4(hv[0], hv[1], hv[2], hv[3]);
        *(uint4*)&Asl[off] = make_uint4(lv[0], lv[1], lv[2], lv[3]);
      }
      *(uint4*)&Bsh[off] = *(const uint4*)&Bh[(size_t)(col0 + r) * K + k0 + kk];
      *(uint4*)&Bsl[off] = *(const uint4*)&Bl[(size_t)(col0 + r) * K + k0 + kk];
    }
    __syncthreads();
    s16x8 ah[4], al[4], bh[4], bl[4];
#pragma unroll
    for (int m = 0; m < 4; ++m){
      int row = wm*64 + m*16 + lr;
      int aoff = (row << 5) + ((lg ^ ((row >> 1) & 3)) << 3);
      ah[m] = *(const s16x8*)&Ash[aoff];
      al[m] = *(const s16x8*)&Asl[aoff];
    }
#pragma unroll
    for (int n = 0; n < 4; ++n){
      int row = wn*64 + n*16 + lr;
      int boff = (row << 5) + ((lg ^ ((row >> 1) & 3)) << 3);
      bh[n] = *(const s16x8*)&Bsh[boff];
      bl[n] = *(const s16x8*)&Bsl[boff];
    }
#pragma unroll
    for (int m = 0; m < 4; ++m)
#pragma unroll
      for (int n = 0; n < 4; ++n){
        acc[m][n] = __builtin_amdgcn_mfma_f32_16x16x32_bf16(ah[m], bh[n], acc[m][n], 0, 0, 0);
        acc[m][n] = __builtin_amdgcn_mfma_f32_16x16x32_bf16(ah[m], bl[n], acc[m][n], 0, 0, 0);
        acc[m][n] = __builtin_amdgcn_mfma_f32_16x16x32_bf16(al[m], bh[n], acc[m][n], 0, 0, 0);
      }
  }

#pragma unroll
  for (int m = 0; m < 4; ++m){
    int grow_base = row0 + wm*64 + m*16 + lg*4;
#pragma unroll
    for (int n = 0; n < 4; ++n){
      int gcol = col0 + wn*64 + n*16 + lr;
      float bv = bias[gcol];
      if (OUTMODE == 1){
        float4 o; float* op = (float*)&o;
#pragma unroll
        for (int r = 0; r < 4; ++r){
          float v2 = acc[m][n][r] + bv;
          if (ACT) v2 = v2 / (1.f + __expf(-v2));
          op[r] = v2;
        }
        int bb = grow_base >> 11, t = grow_base & 2047;
        *(float4*)&C[((size_t)bb * N + gcol) * 2048 + t] = o;
      } else {
#pragma unroll
        for (int r = 0; r < 4; ++r){
          float v2 = acc[m][n][r] + bv;
          if (ACT) v2 = v2 / (1.f + __expf(-v2));
          int grow = grow_base + r;
          if (OUTMODE == 0){
            C[(size_t)grow * N + gcol] = v2;
          } else {
            unsigned short hh = f2bf(v2);
            Ch[(size_t)grow * N + gcol] = hh;
            Cl[(size_t)grow * N + gcol] = f2bf(v2 - bf2f(hh));
          }
        }
      }
    }
  }
}

// ---------------- small kernels ----------------
__global__ __launch_bounds__(256)
void pos_init(const float* __restrict__ pw, const float* __restrict__ pb, float* __restrict__ h){
  int idx = blockIdx.x * 256 + threadIdx.x;
  int t = idx >> 9, r = idx & 511;
  h[idx] = (float)t * pw[r] + pb[r];
}

// srms + relu + bf16 hi/lo split (feeds MFMA pos-MLP GEMMs)
__global__ __launch_bounds__(256)
void srms_relu_split(const float* __restrict__ in, ushort* __restrict__ oh,
                     ushort* __restrict__ ol){
  __shared__ float red[256];
  int row = blockIdx.x, tid = threadIdx.x;
  const float* r = in + (size_t)row * 512;
  float a = r[tid], b = r[tid + 256];
  red[tid] = a*a + b*b;
  __syncthreads();
  for (int off = 128; off > 0; off >>= 1){
    if (tid < off) red[tid] += red[tid + off];
    __syncthreads();
  }
  float rms = sqrtf(red[0] * (1.f / 512.f));
  float inv = 1.f / (rms + EPS_);
  size_t base = (size_t)row * 512;
  float va = a * inv; va = va > 0.f ? va : 0.f;
  float vb = b * inv; vb = vb > 0.f ? vb : 0.f;
  unsigned short ha = f2bf(va), hb = f2bf(vb);
  oh[base + tid]       = ha; ol[base + tid]       = f2bf(va - bf2f(ha));
  oh[base + tid + 256] = hb; ol[base + tid + 256] = f2bf(vb - bf2f(hb));
}

// Build A-spectra for pairs [pbase, pbase+gridDim.x): channels (2p,2p+1)
__global__ __launch_bounds__(256)
void build_aspec(const float* __restrict__ coefs_t, float2* __restrict__ aspec, int pbase){
  __shared__ float2 z[4096];
  __shared__ float2 tw[2048];
  int tid = threadIdx.x, slot = blockIdx.x, p = pbase + slot;
  tw_init(tw, tid);
  const float* c0 = coefs_t + (size_t)(2*p) * 2048;
  const float* c1 = c0 + 2048;
  const float l2g = log2f(GAMMA_);
  for (int t = tid; t < 2048; t += 256){
    float g = exp2f(l2g * (float)t);
    z[t] = make_float2(c0[t] * g, c1[t] * g);
  }
  for (int t = 2048 + tid; t < 4096; t += 256) z[t] = make_float2(0.f, 0.f);
  fft_dif(z, tw, tid);
  for (int k = tid; k <= 2048; k += 256){
    float2 zk = z[rev12(k)];
    float2 zm = z[rev12((4096 - k) & 4095)];
    float2 A0 = make_float2(0.5f*(zk.x + zm.x),  0.5f*(zk.y - zm.y));
    float2 A1 = make_float2(0.5f*(zk.y + zm.y), -0.5f*(zk.x - zm.x));
    *(float4*)(aspec + ((size_t)slot * 2049 + k) * 2) = make_float4(A0.x, A0.y, A1.x, A1.y);
  }
}

// Conv for pairs [pbase, pbase+gridDim.x): FFT, pointwise, inverse; in-place on vt
__global__ __launch_bounds__(256)
void conv_fft(float* __restrict__ vt, const float4* __restrict__ aspec, int pbase){
  __shared__ float2 z[4096];
  __shared__ float2 tw[2048];
  int tid = threadIdx.x, slot = blockIdx.x, p = pbase + slot, bb = blockIdx.y;
  tw_init(tw, tid);
  float* v0 = vt + ((size_t)bb * 3072 + 2*p) * 2048;
  float* v1 = v0 + 2048;
  for (int t = tid; t < 2048; t += 256) z[t] = make_float2(v0[t], v1[t]);
  for (int t = 2048 + tid; t < 4096; t += 256) z[t] = make_float2(0.f, 0.f);
  fft_dif(z, tw, tid);
  for (int k = tid; k <= 2048; k += 256){
    int rk  = rev12(k);
    int rmk = rev12((4096 - k) & 4095);
    float2 zk = z[rk], zm = z[rmk];
    float2 V0 = make_float2(0.5f*(zk.x + zm.x),  0.5f*(zk.y - zm.y));
    float2 V1 = make_float2(0.5f*(zk.y + zm.y), -0.5f*(zk.x - zm.x));
    float4 av = aspec[(size_t)slot * 2049 + k];
    float2 P0 = cmul(V0, make_float2(av.x, av.y));
    float2 P1 = cmul(V1, make_float2(av.z, av.w));
    z[rk]  = make_float2(P0.x - P1.y, -(P0.y + P1.x));
    z[rmk] = make_float2(P0.x + P1.y,   P0.y - P1.x);
  }
  fft_dit(z, tw, tid);
  const float sc = 1.f / 4096.f;
  for (int t = tid; t < 2048; t += 256){
    float2 w = z[t];
    v0[t] =  w.x * sc;
    v1[t] = -w.y * sc;
  }
}

// P = u .* tv written IN PLACE over u (hi/lo). Each element read+written by the
// same thread, so aliasing is race-free. No __restrict__ on uh/ul.
__global__ __launch_bounds__(256)
void fuse_mul_inplace(ushort* uh, ushort* ul, const float* __restrict__ vt){
  __shared__ float T[64][65];
  int tid = threadIdx.x;
  int c0 = blockIdx.x * 64, t0 = blockIdx.y * 64;
  size_t b = blockIdx.z;
  {
    int j = tid >> 2, q = tid & 3;
    const float* src = vt + ((b * 3072 + c0 + j) * 2048 + t0 + q * 16);
#pragma unroll
    for (int f = 0; f < 4; ++f){
      float4 v = *(const float4*)(src + f * 4);
      T[j][q*16 + f*4 + 0] = v.x;
      T[j][q*16 + f*4 + 1] = v.y;
      T[j][q*16 + f*4 + 2] = v.z;
      T[j][q*16 + f*4 + 3] = v.w;
    }
  }
  __syncthreads();
  int i = tid >> 2, q = tid & 3;
  size_t orow = b * 2048 + t0 + i;
#pragma unroll
  for (int f = 0; f < 4; ++f){
    int jc = q*16 + f*4;
    ushort4 hv = *(const ushort4*)&uh[orow * 3072 + c0 + jc];
    ushort4 lv = *(const ushort4*)&ul[orow * 3072 + c0 + jc];
    ushort4 oh, ol;
    float uu, pp; unsigned short hh;
    uu = bf2f(hv.x) + bf2f(lv.x); pp = uu * T[jc+0][i];
    hh = f2bf(pp); oh.x = hh; ol.x = f2bf(pp - bf2f(hh));
    uu = bf2f(hv.y) + bf2f(lv.y); pp = uu * T[jc+1][i];
    hh = f2bf(pp); oh.y = hh; ol.y = f2bf(pp - bf2f(hh));
    uu = bf2f(hv.z) + bf2f(lv.z); pp = uu * T[jc+2][i];
    hh = f2bf(pp); oh.z = hh; ol.z = f2bf(pp - bf2f(hh));
    uu = bf2f(hv.w) + bf2f(lv.w); pp = uu * T[jc+3][i];
    hh = f2bf(pp); oh.w = hh; ol.w = f2bf(pp - bf2f(hh));
    *(ushort4*)&uh[orow * 3072 + c0 + jc] = oh;
    *(ushort4*)&ul[orow * 3072 + c0 + jc] = ol;
  }
}

extern "C" void kernel_launch(void* const* d_in, const int* in_sizes, int n_in,
                              void* d_out, int out_size, void* d_ws, size_t ws_size,
                              hipStream_t stream)
{
  const float* x     = (const float*)d_in[0];
  const float* u_w   = (const float*)d_in[1];
  const float* u_b   = (const float*)d_in[2];
  const float* v_w   = (const float*)d_in[3];
  const float* v_b   = (const float*)d_in[4];
  const float* o_w   = (const float*)d_in[5];
  const float* o_b   = (const float*)d_in[6];
  const float* pos_w = (const float*)d_in[7];
  const float* pos_b = (const float*)d_in[8];
  const float* lw0   = (const float*)d_in[9];
  const float* lb0   = (const float*)d_in[10];
  const float* lw1   = (const float*)d_in[11];
  const float* lb1   = (const float*)d_in[12];
  const float* lw2   = (const float*)d_in[13];
  const float* lb2   = (const float*)d_in[14];
  const float* out_w = (const float*)d_in[15];
  const float* out_b = (const float*)d_in[16];
  float* out = (float*)d_out;

  // Footprint: 201,326,592 persistent + 17,825,792 alias = 219,152,384 B (209 MiB).
  // coefs_t lives in d_out (25.2 MB of 33.5 MB; final GEMM overwrites all of d_out).
  // Diagnostic guard: too-small ws -> clean wrong-answer (poison stays), not a crash.
  if (ws_size < 219152384) return;

  char* ws = (char*)d_ws;
  // ---- persistent region (201,326,592 B) ----
  ushort* uhi  = (ushort*)(ws);                    // 50,331,648  (u, later P hi)
  ushort* ulo  = (ushort*)(ws + 50331648);         // 50,331,648  (u, later P lo)
  float*  vt   = (float*) (ws + 100663296);        // 100,663,296 (v, later tv)
  // ---- alias region R (extent 17,825,792 B) ----
  char* R = ws + 201326592;
  // phase A (u/v GEMMs): weight-transpose slot, serialized u_w then v_w
  ushort* wT_h   = (ushort*)(R);                   // 6,291,456
  ushort* wT_l   = (ushort*)(R + 6291456);         // 6,291,456  -> end 12,582,912
  // phase B (pos-MLP; starts after v-GEMM):
  ushort* hb_h   = (ushort*)(R);                   // 2,097,152
  ushort* hb_l   = (ushort*)(R + 2097152);         // 2,097,152
  ushort* owtT_h = (ushort*)(R + 4194304);         // 3,145,728  (out_w^T hi)
  ushort* owtT_l = (ushort*)(R + 7340032);         // 3,145,728  -> end 10,485,760
  float*  h_a    = (float*) (R + 10485760);        // 4,194,304  -> end 14,680,064
  ushort* lw0T_h = (ushort*)(R + 14680064);        // 524,288 each
  ushort* lw0T_l = (ushort*)(R + 15204352);
  ushort* lw1T_h = (ushort*)(R + 15728640);
  ushort* lw1T_l = (ushort*)(R + 16252928);
  ushort* lw2T_h = (ushort*)(R + 16777216);
  ushort* lw2T_l = (ushort*)(R + 17301504);        // -> end 17,825,792
  float*  coefs_t= (float*)d_out;                  // 25,165,824 in d_out (33.5 MB)
  // phase B2 (spectra passes; hb/owtT dead): 256 pairs/pass
  float2* aspec  = (float2*)(R);                   // 8,392,704 per pass
  // phase C (after conv done; aspec dead): o_w^T for the final GEMM
  ushort* owT_h  = (ushort*)(R);                   // 6,291,456
  ushort* owT_l  = (ushort*)(R + 6291456);         // 6,291,456

  dim3 blk(256);
  // ---- phase A: u/v GEMMs read x fp32 directly (ASRC=1, on-the-fly split) ----
  transpose_split<<<dim3(96, 32), blk, 0, stream>>>(u_w, wT_h, wT_l, 1024, 3072);
  gemm_mfma<1,2,1><<<dim3(24, 64), blk, 0, stream>>>(x, nullptr, nullptr, wT_h, wT_l, u_b,
                                                     nullptr, uhi, ulo, 8192, 3072, 1024);
  transpose_split<<<dim3(96, 32), blk, 0, stream>>>(v_w, wT_h, wT_l, 1024, 3072);
  gemm_mfma<1,1,1><<<dim3(24, 64), blk, 0, stream>>>(x, nullptr, nullptr, wT_h, wT_l, v_b,
                                                     vt, nullptr, nullptr, 8192, 3072, 1024);
  // ---- phase B: position MLP (split-bf16 MFMA); coefs land in d_out ----
  pos_init<<<4096, blk, 0, stream>>>(pos_w, pos_b, h_a);
  transpose_split<<<dim3(16, 16), blk, 0, stream>>>(lw0, lw0T_h, lw0T_l, 512, 512);
  transpose_split<<<dim3(16, 16), blk, 0, stream>>>(lw1, lw1T_h, lw1T_l, 512, 512);
  transpose_split<<<dim3(16, 16), blk, 0, stream>>>(lw2, lw2T_h, lw2T_l, 512, 512);
  transpose_split<<<dim3(96, 16), blk, 0, stream>>>(out_w, owtT_h, owtT_l, 512, 3072);
  srms_relu_split<<<2048, blk, 0, stream>>>(h_a, hb_h, hb_l);
  gemm_mfma<0,0,0><<<dim3(4, 16), blk, 0, stream>>>(nullptr, hb_h, hb_l, lw0T_h, lw0T_l, lb0,
                                                    h_a, nullptr, nullptr, 2048, 512, 512);
  srms_relu_split<<<2048, blk, 0, stream>>>(h_a, hb_h, hb_l);
  gemm_mfma<0,0,0><<<dim3(4, 16), blk, 0, stream>>>(nullptr, hb_h, hb_l, lw1T_h, lw1T_l, lb1,
                                                    h_a, nullptr, nullptr, 2048, 512, 512);
  srms_relu_split<<<2048, blk, 0, stream>>>(h_a, hb_h, hb_l);
  gemm_mfma<0,0,0><<<dim3(4, 16), blk, 0, stream>>>(nullptr, hb_h, hb_l, lw2T_h, lw2T_l, lb2,
                                                    h_a, nullptr, nullptr, 2048, 512, 512);
  srms_relu_split<<<2048, blk, 0, stream>>>(h_a, hb_h, hb_l);
  // coefs_t[c][t] via OUTMODE 1 (M=2048 -> bb=0); written into d_out scratch
  gemm_mfma<0,1,0><<<dim3(24, 16), blk, 0, stream>>>(nullptr, hb_h, hb_l, owtT_h, owtT_l, out_b,
                                                     coefs_t, nullptr, nullptr, 2048, 3072, 512);
  // ---- FFT convolution: 6 passes of 256 channel pairs (aspec buffer reused) ----
  for (int pass = 0; pass < 6; ++pass){
    build_aspec<<<256, blk, 0, stream>>>(coefs_t, aspec, pass * 256);
    conv_fft<<<dim3(256, 4), blk, 0, stream>>>(vt, (const float4*)aspec, pass * 256);
  }
  // ---- phase C: o_w^T, then P = u .* tv in place, then out = P @ o_w + o_b ----
  transpose_split<<<dim3(32, 96), blk, 0, stream>>>(o_w, owT_h, owT_l, 3072, 1024);
  fuse_mul_inplace<<<dim3(48, 32, 4), blk, 0, stream>>>(uhi, ulo, vt);
  gemm_mfma<0,0,0><<<dim3(8, 64), blk, 0, stream>>>(nullptr, uhi, ulo, owT_h, owT_l, o_b,
                                                    out, nullptr, nullptr, 8192, 1024, 3072);
}

// Round 9
// 1275.963 us; speedup vs baseline: 1.0557x; 1.0211x over previous
//
#include <hip/hip_runtime.h>
#include <hip/hip_bf16.h>
#include <math.h>

#define GAMMA_ 0.99f
#define EPS_ 1e-8f

typedef __attribute__((ext_vector_type(8))) short s16x8;
typedef __attribute__((ext_vector_type(4))) float f32x4;
typedef __attribute__((address_space(1))) const ushort GASu;
typedef __attribute__((address_space(3))) ushort LASu;

__device__ __forceinline__ unsigned short f2bf(float f){
  unsigned u = __float_as_uint(f);
  unsigned r = (u + 0x7FFFu + ((u >> 16) & 1u)) >> 16;
  return (unsigned short)r;
}
__device__ __forceinline__ float bf2f(unsigned short h){
  return __uint_as_float(((unsigned)h) << 16);
}

__device__ __forceinline__ float2 cmul(float2 a, float2 b){
  return make_float2(a.x*b.x - a.y*b.y, a.x*b.y + a.y*b.x);
}
__device__ __forceinline__ float2 cadd(float2 a, float2 b){ return make_float2(a.x+b.x, a.y+b.y); }
__device__ __forceinline__ float2 csub(float2 a, float2 b){ return make_float2(a.x-b.x, a.y-b.y); }

// ---------------- FFT (4096-pt complex, 256 threads, LDS-resident) ----------------
__device__ void fft_dif(float2* z, const float2* tw, int tid){
  for (int s = 0; s < 12; ++s){
    __syncthreads();
    int half = 2048 >> s;
    for (int b = tid; b < 2048; b += 256){
      int j  = b & (half - 1);
      int g  = b >> (11 - s);
      int i0 = (g << (12 - s)) + j;
      int i1 = i0 + half;
      float2 u = z[i0], v = z[i1];
      z[i0] = cadd(u, v);
      z[i1] = cmul(csub(u, v), tw[j << s]);
    }
  }
  __syncthreads();
}
__device__ void fft_dit(float2* z, const float2* tw, int tid){
  for (int s = 0; s < 12; ++s){
    __syncthreads();
    int half = 1 << s;
    for (int b = tid; b < 2048; b += 256){
      int j  = b & (half - 1);
      int g  = b >> s;
      int i0 = (g << (s + 1)) + j;
      int i1 = i0 + half;
      float2 u = z[i0];
      float2 t = cmul(z[i1], tw[j << (11 - s)]);
      z[i0] = cadd(u, t);
      z[i1] = csub(u, t);
    }
  }
  __syncthreads();
}
__device__ __forceinline__ void tw_init(float2* tw, int tid){
  for (int j = tid; j < 2048; j += 256){
    float th = -(float)(3.14159265358979323846 / 2048.0) * (float)j;
    float s_, c_; __sincosf(th, &s_, &c_);
    tw[j] = make_float2(c_, s_);
  }
}
__device__ __forceinline__ int rev12(int x){ return (int)(__brev((unsigned)x) >> 20); }

// ---------------- transpose + split prep kernel ----------------
// W [K][N] fp32 -> Th/Tl [N][K] bf16 (tiled transpose + split)
__global__ __launch_bounds__(256)
void transpose_split(const float* __restrict__ W, ushort* __restrict__ Th,
                     ushort* __restrict__ Tl, int K, int N){
  __shared__ float T[32][33];
  int n0 = blockIdx.x * 32, k0 = blockIdx.y * 32;
  int tid = threadIdx.x;
  int j = tid & 31, i = tid >> 5;         // i in 0..7
#pragma unroll
  for (int p = 0; p < 4; ++p)
    T[i + 8*p][j] = W[(size_t)(k0 + i + 8*p) * N + n0 + j];
  __syncthreads();
#pragma unroll
  for (int p = 0; p < 4; ++p){
    int r = i + 8*p;                      // output row n0+r, col k0+j
    float f = T[j][r];
    unsigned short hh = f2bf(f);
    Th[(size_t)(n0 + r) * K + k0 + j] = hh;
    Tl[(size_t)(n0 + r) * K + k0 + j] = f2bf(f - bf2f(hh));
  }
}

// ---------------- split-bf16 MFMA GEMM ----------------
// C = act(A @ B^T + bias), B=[N][K] bf16 pair.
// ASRC 0: A = bf16 hi/lo pair [M][K] (Ah/Al), staged via global_load_lds.
// ASRC 1: A = fp32 [M][K] (Af), split to hi/lo in registers during staging.
// B always staged via global_load_lds (direct HBM->LDS, no VGPR round-trip).
// OUTMODE 0: fp32 row-major [M][N]
// OUTMODE 1: fp32 channel-major C[((row>>11)*N + col)*2048 + (row&2047)]
// OUTMODE 2: bf16 hi/lo pair row-major [M][N]
//
// LDS: unpadded [128][32] ushort (64B rows), 16B-chunk XOR swizzle
//   physical_chunk = logical_chunk ^ ((row>>1)&3)
// global_load_lds writes LINEARLY (wave base + lane*16), so the per-lane
// GLOBAL source address is inverse-swizzled (XOR is an involution) and the
// read side applies the same swizzle -> bank-conflict-free, bytes identical.
template<int ACT, int OUTMODE, int ASRC>
__global__ __launch_bounds__(256)
void gemm_mfma(const float* __restrict__ Af,
               const ushort* __restrict__ Ah, const ushort* __restrict__ Al,
               const ushort* __restrict__ Bh, const ushort* __restrict__ Bl,
               const float* __restrict__ bias,
               float* __restrict__ C, ushort* __restrict__ Ch, ushort* __restrict__ Cl,
               int M, int N, int K)
{
  __shared__ ushort Ash[128*32];
  __shared__ ushort Asl[128*32];
  __shared__ ushort Bsh[128*32];
  __shared__ ushort Bsl[128*32];
  int tid = threadIdx.x;
  // XCD-aware bijective swizzle (nwg % 8 == 0 for all our launches)
  int gx = gridDim.x;
  int nwg = gx * gridDim.y;
  int flat = blockIdx.y * gx + blockIdx.x;
  int s = (flat & 7) * (nwg >> 3) + (flat >> 3);
  int bx = s % gx, by = s / gx;
  int row0 = by * 128, col0 = bx * 128;
  int w = tid >> 6, lane = tid & 63;
  int wm = w >> 1, wn = w & 1;
  int lr = lane & 15, lg = lane >> 4;
  f32x4 acc[4][4] = {};

  for (int k0 = 0; k0 < K; k0 += 32){
    __syncthreads();
    // ---- direct HBM->LDS staging (B always; A too when ASRC==0) ----
#pragma unroll
    for (int i = 0; i < 2; ++i){
      int p   = (w << 7) + (i << 6) + lane;   // physical 16B chunk 0..511
      int r   = p >> 2, chp = p & 3;
      int ch  = chp ^ ((r >> 1) & 3);         // inverse-swizzled source chunk
      int lbase = (w << 10) + (i << 9);       // wave-uniform LDS base (ushorts)
      size_t gb = (size_t)(col0 + r) * K + k0 + (ch << 3);
      __builtin_amdgcn_global_load_lds((GASu*)(Bh + gb), (LASu*)(Bsh + lbase), 16, 0, 0);
      __builtin_amdgcn_global_load_lds((GASu*)(Bl + gb), (LASu*)(Bsl + lbase), 16, 0, 0);
      if (ASRC == 0){
        size_t ga = (size_t)(row0 + r) * K + k0 + (ch << 3);
        __builtin_amdgcn_global_load_lds((GASu*)(Ah + ga), (LASu*)(Ash + lbase), 16, 0, 0);
        __builtin_amdgcn_global_load_lds((GASu*)(Al + ga), (LASu*)(Asl + lbase), 16, 0, 0);
      }
    }
    // ---- register staging with fp32->bf16 split (A when ASRC==1) ----
    if (ASRC == 1){
#pragma unroll
      for (int pp = 0; pp < 2; ++pp){
        int c = tid + (pp << 8);
        int r = c >> 2, ch = c & 3;
        int kk = ch << 3;
        int off = (r << 5) + ((ch ^ ((r >> 1) & 3)) << 3);
        const float* src = &Af[(size_t)(row0 + r) * K + k0 + kk];
        float4 f0 = *(const float4*)src;
        float4 f1 = *(const float4*)(src + 4);
        float fs[8] = {f0.x, f0.y, f0.z, f0.w, f1.x, f1.y, f1.z, f1.w};
        uint hv[4], lv[4];
#pragma unroll
        for (int q = 0; q < 4; ++q){
          unsigned short h0 = f2bf(fs[2*q]),     h1 = f2bf(fs[2*q+1]);
          unsigned short l0 = f2bf(fs[2*q]   - bf2f(h0));
          unsigned short l1 = f2bf(fs[2*q+1] - bf2f(h1));
          hv[q] = (uint)h0 | ((uint)h1 << 16);
          lv[q] = (uint)l0 | ((uint)l1 << 16);
        }
        *(uint4*)&Ash[off] = make_uint4(hv[0], hv[1], hv[2], hv[3]);
        *(uint4*)&Asl[off] = make_uint4(lv[0], lv[1], lv[2], lv[3]);
      }
    }
    __syncthreads();
    s16x8 ah[4], al[4], bh[4], bl[4];
#pragma unroll
    for (int m = 0; m < 4; ++m){
      int row = wm*64 + m*16 + lr;
      int aoff = (row << 5) + ((lg ^ ((row >> 1) & 3)) << 3);
      ah[m] = *(const s16x8*)&Ash[aoff];
      al[m] = *(const s16x8*)&Asl[aoff];
    }
#pragma unroll
    for (int n = 0; n < 4; ++n){
      int row = wn*64 + n*16 + lr;
      int boff = (row << 5) + ((lg ^ ((row >> 1) & 3)) << 3);
      bh[n] = *(const s16x8*)&Bsh[boff];
      bl[n] = *(const s16x8*)&Bsl[boff];
    }
#pragma unroll
    for (int m = 0; m < 4; ++m)
#pragma unroll
      for (int n = 0; n < 4; ++n){
        acc[m][n] = __builtin_amdgcn_mfma_f32_16x16x32_bf16(ah[m], bh[n], acc[m][n], 0, 0, 0);
        acc[m][n] = __builtin_amdgcn_mfma_f32_16x16x32_bf16(ah[m], bl[n], acc[m][n], 0, 0, 0);
        acc[m][n] = __builtin_amdgcn_mfma_f32_16x16x32_bf16(al[m], bh[n], acc[m][n], 0, 0, 0);
      }
  }

#pragma unroll
  for (int m = 0; m < 4; ++m){
    int grow_base = row0 + wm*64 + m*16 + lg*4;
#pragma unroll
    for (int n = 0; n < 4; ++n){
      int gcol = col0 + wn*64 + n*16 + lr;
      float bv = bias[gcol];
      if (OUTMODE == 1){
        float4 o; float* op = (float*)&o;
#pragma unroll
        for (int r = 0; r < 4; ++r){
          float v2 = acc[m][n][r] + bv;
          if (ACT) v2 = v2 / (1.f + __expf(-v2));
          op[r] = v2;
        }
        int bb = grow_base >> 11, t = grow_base & 2047;
        *(float4*)&C[((size_t)bb * N + gcol) * 2048 + t] = o;
      } else {
#pragma unroll
        for (int r = 0; r < 4; ++r){
          float v2 = acc[m][n][r] + bv;
          if (ACT) v2 = v2 / (1.f + __expf(-v2));
          int grow = grow_base + r;
          if (OUTMODE == 0){
            C[(size_t)grow * N + gcol] = v2;
          } else {
            unsigned short hh = f2bf(v2);
            Ch[(size_t)grow * N + gcol] = hh;
            Cl[(size_t)grow * N + gcol] = f2bf(v2 - bf2f(hh));
          }
        }
      }
    }
  }
}

// ---------------- small kernels ----------------
__global__ __launch_bounds__(256)
void pos_init(const float* __restrict__ pw, const float* __restrict__ pb, float* __restrict__ h){
  int idx = blockIdx.x * 256 + threadIdx.x;
  int t = idx >> 9, r = idx & 511;
  h[idx] = (float)t * pw[r] + pb[r];
}

// srms + relu + bf16 hi/lo split (feeds MFMA pos-MLP GEMMs)
__global__ __launch_bounds__(256)
void srms_relu_split(const float* __restrict__ in, ushort* __restrict__ oh,
                     ushort* __restrict__ ol){
  __shared__ float red[256];
  int row = blockIdx.x, tid = threadIdx.x;
  const float* r = in + (size_t)row * 512;
  float a = r[tid], b = r[tid + 256];
  red[tid] = a*a + b*b;
  __syncthreads();
  for (int off = 128; off > 0; off >>= 1){
    if (tid < off) red[tid] += red[tid + off];
    __syncthreads();
  }
  float rms = sqrtf(red[0] * (1.f / 512.f));
  float inv = 1.f / (rms + EPS_);
  size_t base = (size_t)row * 512;
  float va = a * inv; va = va > 0.f ? va : 0.f;
  float vb = b * inv; vb = vb > 0.f ? vb : 0.f;
  unsigned short ha = f2bf(va), hb = f2bf(vb);
  oh[base + tid]       = ha; ol[base + tid]       = f2bf(va - bf2f(ha));
  oh[base + tid + 256] = hb; ol[base + tid + 256] = f2bf(vb - bf2f(hb));
}

// Build A-spectra for pairs [pbase, pbase+gridDim.x): channels (2p,2p+1)
__global__ __launch_bounds__(256)
void build_aspec(const float* __restrict__ coefs_t, float2* __restrict__ aspec, int pbase){
  __shared__ float2 z[4096];
  __shared__ float2 tw[2048];
  int tid = threadIdx.x, slot = blockIdx.x, p = pbase + slot;
  tw_init(tw, tid);
  const float* c0 = coefs_t + (size_t)(2*p) * 2048;
  const float* c1 = c0 + 2048;
  const float l2g = log2f(GAMMA_);
  for (int t = tid; t < 2048; t += 256){
    float g = exp2f(l2g * (float)t);
    z[t] = make_float2(c0[t] * g, c1[t] * g);
  }
  for (int t = 2048 + tid; t < 4096; t += 256) z[t] = make_float2(0.f, 0.f);
  fft_dif(z, tw, tid);
  for (int k = tid; k <= 2048; k += 256){
    float2 zk = z[rev12(k)];
    float2 zm = z[rev12((4096 - k) & 4095)];
    float2 A0 = make_float2(0.5f*(zk.x + zm.x),  0.5f*(zk.y - zm.y));
    float2 A1 = make_float2(0.5f*(zk.y + zm.y), -0.5f*(zk.x - zm.x));
    *(float4*)(aspec + ((size_t)slot * 2049 + k) * 2) = make_float4(A0.x, A0.y, A1.x, A1.y);
  }
}

// Conv for pairs [pbase, pbase+gridDim.x): FFT, pointwise, inverse; in-place on vt
__global__ __launch_bounds__(256)
void conv_fft(float* __restrict__ vt, const float4* __restrict__ aspec, int pbase){
  __shared__ float2 z[4096];
  __shared__ float2 tw[2048];
  int tid = threadIdx.x, slot = blockIdx.x, p = pbase + slot, bb = blockIdx.y;
  tw_init(tw, tid);
  float* v0 = vt + ((size_t)bb * 3072 + 2*p) * 2048;
  float* v1 = v0 + 2048;
  for (int t = tid; t < 2048; t += 256) z[t] = make_float2(v0[t], v1[t]);
  for (int t = 2048 + tid; t < 4096; t += 256) z[t] = make_float2(0.f, 0.f);
  fft_dif(z, tw, tid);
  for (int k = tid; k <= 2048; k += 256){
    int rk  = rev12(k);
    int rmk = rev12((4096 - k) & 4095);
    float2 zk = z[rk], zm = z[rmk];
    float2 V0 = make_float2(0.5f*(zk.x + zm.x),  0.5f*(zk.y - zm.y));
    float2 V1 = make_float2(0.5f*(zk.y + zm.y), -0.5f*(zk.x - zm.x));
    float4 av = aspec[(size_t)slot * 2049 + k];
    float2 P0 = cmul(V0, make_float2(av.x, av.y));
    float2 P1 = cmul(V1, make_float2(av.z, av.w));
    z[rk]  = make_float2(P0.x - P1.y, -(P0.y + P1.x));
    z[rmk] = make_float2(P0.x + P1.y,   P0.y - P1.x);
  }
  fft_dit(z, tw, tid);
  const float sc = 1.f / 4096.f;
  for (int t = tid; t < 2048; t += 256){
    float2 w = z[t];
    v0[t] =  w.x * sc;
    v1[t] = -w.y * sc;
  }
}

// P = u .* tv written IN PLACE over u (hi/lo), 16B fully-coalesced accesses.
// Each element read+written by the same thread -> race-free. No __restrict__ on uh/ul.
__global__ __launch_bounds__(256)
void fuse_mul_inplace(ushort* uh, ushort* ul, const float* __restrict__ vt){
  __shared__ float T[64][65];                 // T[channel][t]
  int tid = threadIdx.x;
  int c0 = blockIdx.x * 64, t0 = blockIdx.y * 64;
  size_t b = blockIdx.z;
  {
    int j = tid >> 2, q = tid & 3;
    const float* src = vt + ((b * 3072 + c0 + j) * 2048 + t0 + q * 16);
#pragma unroll
    for (int f = 0; f < 4; ++f){
      float4 v = *(const float4*)(src + f * 4);
      T[j][q*16 + f*4 + 0] = v.x;
      T[j][q*16 + f*4 + 1] = v.y;
      T[j][q*16 + f*4 + 2] = v.z;
      T[j][q*16 + f*4 + 3] = v.w;
    }
  }
  __syncthreads();
  int i = tid >> 3, jq = tid & 7;             // 32 t-rows x 8 col-groups (8 ch each)
#pragma unroll
  for (int f = 0; f < 2; ++f){
    int row = i + f*32;
    size_t base = ((size_t)b * 2048 + t0 + row) * 3072 + c0 + jq*8;
    uint4 hv = *(const uint4*)&uh[base];
    uint4 lv = *(const uint4*)&ul[base];
    const uint* hp = (const uint*)&hv;
    const uint* lp = (const uint*)&lv;
    uint hr[4], lw[4];
#pragma unroll
    for (int e = 0; e < 4; ++e){
      int ch0 = jq*8 + e*2;
      float u0 = bf2f((unsigned short)(hp[e] & 0xffffu)) + bf2f((unsigned short)(lp[e] & 0xffffu));
      float u1 = bf2f((unsigned short)(hp[e] >> 16))     + bf2f((unsigned short)(lp[e] >> 16));
      float p0 = u0 * T[ch0][row];
      float p1 = u1 * T[ch0 + 1][row];
      unsigned short h0 = f2bf(p0), l0 = f2bf(p0 - bf2f(h0));
      unsigned short h1 = f2bf(p1), l1 = f2bf(p1 - bf2f(h1));
      hr[e] = (uint)h0 | ((uint)h1 << 16);
      lw[e] = (uint)l0 | ((uint)l1 << 16);
    }
    *(uint4*)&uh[base] = make_uint4(hr[0], hr[1], hr[2], hr[3]);
    *(uint4*)&ul[base] = make_uint4(lw[0], lw[1], lw[2], lw[3]);
  }
}

extern "C" void kernel_launch(void* const* d_in, const int* in_sizes, int n_in,
                              void* d_out, int out_size, void* d_ws, size_t ws_size,
                              hipStream_t stream)
{
  const float* x     = (const float*)d_in[0];
  const float* u_w   = (const float*)d_in[1];
  const float* u_b   = (const float*)d_in[2];
  const float* v_w   = (const float*)d_in[3];
  const float* v_b   = (const float*)d_in[4];
  const float* o_w   = (const float*)d_in[5];
  const float* o_b   = (const float*)d_in[6];
  const float* pos_w = (const float*)d_in[7];
  const float* pos_b = (const float*)d_in[8];
  const float* lw0   = (const float*)d_in[9];
  const float* lb0   = (const float*)d_in[10];
  const float* lw1   = (const float*)d_in[11];
  const float* lb1   = (const float*)d_in[12];
  const float* lw2   = (const float*)d_in[13];
  const float* lb2   = (const float*)d_in[14];
  const float* out_w = (const float*)d_in[15];
  const float* out_b = (const float*)d_in[16];
  float* out = (float*)d_out;

  // Footprint: 201,326,592 persistent + 17,825,792 alias = 219,152,384 B (209 MiB).
  // coefs_t lives in d_out (25.2 MB of 33.5 MB; final GEMM overwrites all of d_out).
  // Diagnostic guard: too-small ws -> clean wrong-answer (poison stays), not a crash.
  if (ws_size < 219152384) return;

  char* ws = (char*)d_ws;
  // ---- persistent region (201,326,592 B) ----
  ushort* uhi  = (ushort*)(ws);                    // 50,331,648  (u, later P hi)
  ushort* ulo  = (ushort*)(ws + 50331648);         // 50,331,648  (u, later P lo)
  float*  vt   = (float*) (ws + 100663296);        // 100,663,296 (v, later tv)
  // ---- alias region R (extent 17,825,792 B) ----
  char* R = ws + 201326592;
  // phase A (u/v GEMMs): weight-transpose slot, serialized u_w then v_w
  ushort* wT_h   = (ushort*)(R);                   // 6,291,456
  ushort* wT_l   = (ushort*)(R + 6291456);         // 6,291,456  -> end 12,582,912
  // phase B (pos-MLP; starts after v-GEMM):
  ushort* hb_h   = (ushort*)(R);                   // 2,097,152
  ushort* hb_l   = (ushort*)(R + 2097152);         // 2,097,152
  ushort* owtT_h = (ushort*)(R + 4194304);         // 3,145,728  (out_w^T hi)
  ushort* owtT_l = (ushort*)(R + 7340032);         // 3,145,728  -> end 10,485,760
  float*  h_a    = (float*) (R + 10485760);        // 4,194,304  -> end 14,680,064
  ushort* lw0T_h = (ushort*)(R + 14680064);        // 524,288 each
  ushort* lw0T_l = (ushort*)(R + 15204352);
  ushort* lw1T_h = (ushort*)(R + 15728640);
  ushort* lw1T_l = (ushort*)(R + 16252928);
  ushort* lw2T_h = (ushort*)(R + 16777216);
  ushort* lw2T_l = (ushort*)(R + 17301504);        // -> end 17,825,792
  float*  coefs_t= (float*)d_out;                  // 25,165,824 in d_out (33.5 MB)
  // phase B2 (spectra passes; hb/owtT dead): 256 pairs/pass
  float2* aspec  = (float2*)(R);                   // 8,392,704 per pass
  // phase C (after conv done; aspec dead): o_w^T for the final GEMM
  ushort* owT_h  = (ushort*)(R);                   // 6,291,456
  ushort* owT_l  = (ushort*)(R + 6291456);         // 6,291,456

  dim3 blk(256);
  // ---- phase A: u/v GEMMs read x fp32 directly (ASRC=1, on-the-fly split) ----
  transpose_split<<<dim3(96, 32), blk, 0, stream>>>(u_w, wT_h, wT_l, 1024, 3072);
  gemm_mfma<1,2,1><<<dim3(24, 64), blk, 0, stream>>>(x, nullptr, nullptr, wT_h, wT_l, u_b,
                                                     nullptr, uhi, ulo, 8192, 3072, 1024);
  transpose_split<<<dim3(96, 32), blk, 0, stream>>>(v_w, wT_h, wT_l, 1024, 3072);
  gemm_mfma<1,1,1><<<dim3(24, 64), blk, 0, stream>>>(x, nullptr, nullptr, wT_h, wT_l, v_b,
                                                     vt, nullptr, nullptr, 8192, 3072, 1024);
  // ---- phase B: position MLP (split-bf16 MFMA); coefs land in d_out ----
  pos_init<<<4096, blk, 0, stream>>>(pos_w, pos_b, h_a);
  transpose_split<<<dim3(16, 16), blk, 0, stream>>>(lw0, lw0T_h, lw0T_l, 512, 512);
  transpose_split<<<dim3(16, 16), blk, 0, stream>>>(lw1, lw1T_h, lw1T_l, 512, 512);
  transpose_split<<<dim3(16, 16), blk, 0, stream>>>(lw2, lw2T_h, lw2T_l, 512, 512);
  transpose_split<<<dim3(96, 16), blk, 0, stream>>>(out_w, owtT_h, owtT_l, 512, 3072);
  srms_relu_split<<<2048, blk, 0, stream>>>(h_a, hb_h, hb_l);
  gemm_mfma<0,0,0><<<dim3(4, 16), blk, 0, stream>>>(nullptr, hb_h, hb_l, lw0T_h, lw0T_l, lb0,
                                                    h_a, nullptr, nullptr, 2048, 512, 512);
  srms_relu_split<<<2048, blk, 0, stream>>>(h_a, hb_h, hb_l);
  gemm_mfma<0,0,0><<<dim3(4, 16), blk, 0, stream>>>(nullptr, hb_h, hb_l, lw1T_h, lw1T_l, lb1,
                                                    h_a, nullptr, nullptr, 2048, 512, 512);
  srms_relu_split<<<2048, blk, 0, stream>>>(h_a, hb_h, hb_l);
  gemm_mfma<0,0,0><<<dim3(4, 16), blk, 0, stream>>>(nullptr, hb_h, hb_l, lw2T_h, lw2T_l, lb2,
                                                    h_a, nullptr, nullptr, 2048, 512, 512);
  srms_relu_split<<<2048, blk, 0, stream>>>(h_a, hb_h, hb_l);
  // coefs_t[c][t] via OUTMODE 1 (M=2048 -> bb=0); written into d_out scratch
  gemm_mfma<0,1,0><<<dim3(24, 16), blk, 0, stream>>>(nullptr, hb_h, hb_l, owtT_h, owtT_l, out_b,
                                                     coefs_t, nullptr, nullptr, 2048, 3072, 512);
  // ---- FFT convolution: 6 passes of 256 channel pairs (aspec buffer reused) ----
  for (int pass = 0; pass < 6; ++pass){
    build_aspec<<<256, blk, 0, stream>>>(coefs_t, aspec, pass * 256);
    conv_fft<<<dim3(256, 4), blk, 0, stream>>>(vt, (const float4*)aspec, pass * 256);
  }
  // ---- phase C: o_w^T, then P = u .* tv in place, then out = P @ o_w + o_b ----
  transpose_split<<<dim3(32, 96), blk, 0, stream>>>(o_w, owT_h, owT_l, 3072, 1024);
  fuse_mul_inplace<<<dim3(48, 32, 4), blk, 0, stream>>>(uhi, ulo, vt);
  gemm_mfma<0,0,0><<<dim3(8, 64), blk, 0, stream>>>(nullptr, uhi, ulo, owT_h, owT_l, o_b,
                                                    out, nullptr, nullptr, 8192, 1024, 3072);
}

// Round 11
// 1225.825 us; speedup vs baseline: 1.0989x; 1.0409x over previous
//
#include <hip/hip_runtime.h>
#include <hip/hip_bf16.h>
#include <math.h>

#define GAMMA_ 0.99f
#define EPS_ 1e-8f

typedef __attribute__((ext_vector_type(8))) short s16x8;
typedef __attribute__((ext_vector_type(4))) float f32x4;
typedef __attribute__((address_space(1))) const ushort GASu;
typedef __attribute__((address_space(3))) ushort LASu;

__device__ __forceinline__ unsigned short f2bf(float f){
  unsigned u = __float_as_uint(f);
  unsigned r = (u + 0x7FFFu + ((u >> 16) & 1u)) >> 16;
  return (unsigned short)r;
}
__device__ __forceinline__ float bf2f(unsigned short h){
  return __uint_as_float(((unsigned)h) << 16);
}

__device__ __forceinline__ float2 cmul(float2 a, float2 b){
  return make_float2(a.x*b.x - a.y*b.y, a.x*b.y + a.y*b.x);
}
__device__ __forceinline__ float2 cadd(float2 a, float2 b){ return make_float2(a.x+b.x, a.y+b.y); }
__device__ __forceinline__ float2 csub(float2 a, float2 b){ return make_float2(a.x-b.x, a.y-b.y); }

// ---------------- FFT (4096-pt complex, 256 threads, LDS-resident) ----------------
__device__ void fft_dif(float2* z, const float2* tw, int tid){
  for (int s = 0; s < 12; ++s){
    __syncthreads();
    int half = 2048 >> s;
    for (int b = tid; b < 2048; b += 256){
      int j  = b & (half - 1);
      int g  = b >> (11 - s);
      int i0 = (g << (12 - s)) + j;
      int i1 = i0 + half;
      float2 u = z[i0], v = z[i1];
      z[i0] = cadd(u, v);
      z[i1] = cmul(csub(u, v), tw[j << s]);
    }
  }
  __syncthreads();
}
__device__ void fft_dit(float2* z, const float2* tw, int tid){
  for (int s = 0; s < 12; ++s){
    __syncthreads();
    int half = 1 << s;
    for (int b = tid; b < 2048; b += 256){
      int j  = b & (half - 1);
      int g  = b >> s;
      int i0 = (g << (s + 1)) + j;
      int i1 = i0 + half;
      float2 u = z[i0];
      float2 t = cmul(z[i1], tw[j << (11 - s)]);
      z[i0] = cadd(u, t);
      z[i1] = csub(u, t);
    }
  }
  __syncthreads();
}
__device__ __forceinline__ void tw_init(float2* tw, int tid){
  for (int j = tid; j < 2048; j += 256){
    float th = -(float)(3.14159265358979323846 / 2048.0) * (float)j;
    float s_, c_; __sincosf(th, &s_, &c_);
    tw[j] = make_float2(c_, s_);
  }
}
__device__ __forceinline__ int rev12(int x){ return (int)(__brev((unsigned)x) >> 20); }

// ---------------- transpose + split prep kernel ----------------
// W [K][N] fp32 -> Th/Tl [N][K] bf16 (tiled transpose + split)
__global__ __launch_bounds__(256)
void transpose_split(const float* __restrict__ W, ushort* __restrict__ Th,
                     ushort* __restrict__ Tl, int K, int N){
  __shared__ float T[32][33];
  int n0 = blockIdx.x * 32, k0 = blockIdx.y * 32;
  int tid = threadIdx.x;
  int j = tid & 31, i = tid >> 5;         // i in 0..7
#pragma unroll
  for (int p = 0; p < 4; ++p)
    T[i + 8*p][j] = W[(size_t)(k0 + i + 8*p) * N + n0 + j];
  __syncthreads();
#pragma unroll
  for (int p = 0; p < 4; ++p){
    int r = i + 8*p;                      // output row n0+r, col k0+j
    float f = T[j][r];
    unsigned short hh = f2bf(f);
    Th[(size_t)(n0 + r) * K + k0 + j] = hh;
    Tl[(size_t)(n0 + r) * K + k0 + j] = f2bf(f - bf2f(hh));
  }
}

// ---------------- split-bf16 MFMA GEMM ----------------
// C = act(A @ B^T + bias), B=[N][K] bf16 pair.
// ASRC 0: A = bf16 hi/lo pair [M][K] (Ah/Al), staged via global_load_lds.
// ASRC 1: A = fp32 [M][K] (Af), split to hi/lo in registers during staging.
// B always staged via global_load_lds (direct HBM->LDS, no VGPR round-trip).
// OUTMODE 0: fp32 row-major [M][N]
// OUTMODE 1: fp32 channel-major C[((row>>11)*N + col)*2048 + (row&2047)]
// OUTMODE 2: bf16 hi/lo pair row-major [M][N]
//
// LDS: unpadded [128][32] ushort (64B rows), 16B-chunk XOR swizzle
//   physical_chunk = logical_chunk ^ ((row>>1)&3)
// global_load_lds writes LINEARLY (wave base + lane*16), so the per-lane
// GLOBAL source address is inverse-swizzled (XOR is an involution) and the
// read side applies the same swizzle -> bank-conflict-free, bytes identical.
template<int ACT, int OUTMODE, int ASRC>
__global__ __launch_bounds__(256)
void gemm_mfma(const float* __restrict__ Af,
               const ushort* __restrict__ Ah, const ushort* __restrict__ Al,
               const ushort* __restrict__ Bh, const ushort* __restrict__ Bl,
               const float* __restrict__ bias,
               float* __restrict__ C, ushort* __restrict__ Ch, ushort* __restrict__ Cl,
               int M, int N, int K)
{
  __shared__ ushort Ash[128*32];
  __shared__ ushort Asl[128*32];
  __shared__ ushort Bsh[128*32];
  __shared__ ushort Bsl[128*32];
  int tid = threadIdx.x;
  // XCD-aware bijective swizzle (nwg % 8 == 0 for all our launches)
  int gx = gridDim.x;
  int nwg = gx * gridDim.y;
  int flat = blockIdx.y * gx + blockIdx.x;
  int s = (flat & 7) * (nwg >> 3) + (flat >> 3);
  int bx = s % gx, by = s / gx;
  int row0 = by * 128, col0 = bx * 128;
  int w = tid >> 6, lane = tid & 63;
  int wm = w >> 1, wn = w & 1;
  int lr = lane & 15, lg = lane >> 4;
  f32x4 acc[4][4] = {};

  for (int k0 = 0; k0 < K; k0 += 32){
    __syncthreads();
    // ---- direct HBM->LDS staging (B always; A too when ASRC==0) ----
#pragma unroll
    for (int i = 0; i < 2; ++i){
      int p   = (w << 7) + (i << 6) + lane;   // physical 16B chunk 0..511
      int r   = p >> 2, chp = p & 3;
      int ch  = chp ^ ((r >> 1) & 3);         // inverse-swizzled source chunk
      int lbase = (w << 10) + (i << 9);       // wave-uniform LDS base (ushorts)
      size_t gb = (size_t)(col0 + r) * K + k0 + (ch << 3);
      __builtin_amdgcn_global_load_lds((GASu*)(Bh + gb), (LASu*)(Bsh + lbase), 16, 0, 0);
      __builtin_amdgcn_global_load_lds((GASu*)(Bl + gb), (LASu*)(Bsl + lbase), 16, 0, 0);
      if (ASRC == 0){
        size_t ga = (size_t)(row0 + r) * K + k0 + (ch << 3);
        __builtin_amdgcn_global_load_lds((GASu*)(Ah + ga), (LASu*)(Ash + lbase), 16, 0, 0);
        __builtin_amdgcn_global_load_lds((GASu*)(Al + ga), (LASu*)(Asl + lbase), 16, 0, 0);
      }
    }
    // ---- register staging with fp32->bf16 split (A when ASRC==1) ----
    if (ASRC == 1){
#pragma unroll
      for (int pp = 0; pp < 2; ++pp){
        int c = tid + (pp << 8);
        int r = c >> 2, ch = c & 3;
        int kk = ch << 3;
        int off = (r << 5) + ((ch ^ ((r >> 1) & 3)) << 3);
        const float* src = &Af[(size_t)(row0 + r) * K + k0 + kk];
        float4 f0 = *(const float4*)src;
        float4 f1 = *(const float4*)(src + 4);
        float fs[8] = {f0.x, f0.y, f0.z, f0.w, f1.x, f1.y, f1.z, f1.w};
        uint hv[4], lv[4];
#pragma unroll
        for (int q = 0; q < 4; ++q){
          unsigned short h0 = f2bf(fs[2*q]),     h1 = f2bf(fs[2*q+1]);
          unsigned short l0 = f2bf(fs[2*q]   - bf2f(h0));
          unsigned short l1 = f2bf(fs[2*q+1] - bf2f(h1));
          hv[q] = (uint)h0 | ((uint)h1 << 16);
          lv[q] = (uint)l0 | ((uint)l1 << 16);
        }
        *(uint4*)&Ash[off] = make_uint4(hv[0], hv[1], hv[2], hv[3]);
        *(uint4*)&Asl[off] = make_uint4(lv[0], lv[1], lv[2], lv[3]);
      }
    }
    __syncthreads();
    s16x8 ah[4], al[4], bh[4], bl[4];
#pragma unroll
    for (int m = 0; m < 4; ++m){
      int row = wm*64 + m*16 + lr;
      int aoff = (row << 5) + ((lg ^ ((row >> 1) & 3)) << 3);
      ah[m] = *(const s16x8*)&Ash[aoff];
      al[m] = *(const s16x8*)&Asl[aoff];
    }
#pragma unroll
    for (int n = 0; n < 4; ++n){
      int row = wn*64 + n*16 + lr;
      int boff = (row << 5) + ((lg ^ ((row >> 1) & 3)) << 3);
      bh[n] = *(const s16x8*)&Bsh[boff];
      bl[n] = *(const s16x8*)&Bsl[boff];
    }
#pragma unroll
    for (int m = 0; m < 4; ++m)
#pragma unroll
      for (int n = 0; n < 4; ++n){
        acc[m][n] = __builtin_amdgcn_mfma_f32_16x16x32_bf16(ah[m], bh[n], acc[m][n], 0, 0, 0);
        acc[m][n] = __builtin_amdgcn_mfma_f32_16x16x32_bf16(ah[m], bl[n], acc[m][n], 0, 0, 0);
        acc[m][n] = __builtin_amdgcn_mfma_f32_16x16x32_bf16(al[m], bh[n], acc[m][n], 0, 0, 0);
      }
  }

#pragma unroll
  for (int m = 0; m < 4; ++m){
    int grow_base = row0 + wm*64 + m*16 + lg*4;
#pragma unroll
    for (int n = 0; n < 4; ++n){
      int gcol = col0 + wn*64 + n*16 + lr;
      float bv = bias[gcol];
      if (OUTMODE == 1){
        float4 o; float* op = (float*)&o;
#pragma unroll
        for (int r = 0; r < 4; ++r){
          float v2 = acc[m][n][r] + bv;
          if (ACT) v2 = v2 / (1.f + __expf(-v2));
          op[r] = v2;
        }
        int bb = grow_base >> 11, t = grow_base & 2047;
        *(float4*)&C[((size_t)bb * N + gcol) * 2048 + t] = o;
      } else {
#pragma unroll
        for (int r = 0; r < 4; ++r){
          float v2 = acc[m][n][r] + bv;
          if (ACT) v2 = v2 / (1.f + __expf(-v2));
          int grow = grow_base + r;
          if (OUTMODE == 0){
            C[(size_t)grow * N + gcol] = v2;
          } else {
            unsigned short hh = f2bf(v2);
            Ch[(size_t)grow * N + gcol] = hh;
            Cl[(size_t)grow * N + gcol] = f2bf(v2 - bf2f(hh));
          }
        }
      }
    }
  }
}

// ---------------- small kernels ----------------
__global__ __launch_bounds__(256)
void pos_init(const float* __restrict__ pw, const float* __restrict__ pb, float* __restrict__ h){
  int idx = blockIdx.x * 256 + threadIdx.x;
  int t = idx >> 9, r = idx & 511;
  h[idx] = (float)t * pw[r] + pb[r];
}

// srms + relu + bf16 hi/lo split (feeds MFMA pos-MLP GEMMs)
__global__ __launch_bounds__(256)
void srms_relu_split(const float* __restrict__ in, ushort* __restrict__ oh,
                     ushort* __restrict__ ol){
  __shared__ float red[256];
  int row = blockIdx.x, tid = threadIdx.x;
  const float* r = in + (size_t)row * 512;
  float a = r[tid], b = r[tid + 256];
  red[tid] = a*a + b*b;
  __syncthreads();
  for (int off = 128; off > 0; off >>= 1){
    if (tid < off) red[tid] += red[tid + off];
    __syncthreads();
  }
  float rms = sqrtf(red[0] * (1.f / 512.f));
  float inv = 1.f / (rms + EPS_);
  size_t base = (size_t)row * 512;
  float va = a * inv; va = va > 0.f ? va : 0.f;
  float vb = b * inv; vb = vb > 0.f ? vb : 0.f;
  unsigned short ha = f2bf(va), hb = f2bf(vb);
  oh[base + tid]       = ha; ol[base + tid]       = f2bf(va - bf2f(ha));
  oh[base + tid + 256] = hb; ol[base + tid + 256] = f2bf(vb - bf2f(hb));
}

// ---------------- fused conv: A-spectrum in registers, loop over 4 batches ----
// One block per channel pair p: build A-spec once (FFT + park in VGPRs),
// then for each batch: FFT(v0 + i*v1), pointwise from registers, inverse, store.
// Eliminates build_aspec kernel, aspec global traffic, and 11 launches.
__global__ __launch_bounds__(256)
void conv_fft_all(float* __restrict__ vt, const float* __restrict__ coefs_t){
  __shared__ float2 z[4096];
  __shared__ float2 tw[2048];
  int tid = threadIdx.x, p = blockIdx.x;
  tw_init(tw, tid);
  // ---- build A-spectrum for this pair ----
  {
    const float* c0 = coefs_t + (size_t)(2*p) * 2048;
    const float* c1 = c0 + 2048;
    const float l2g = log2f(GAMMA_);
    for (int t = tid; t < 2048; t += 256){
      float g = exp2f(l2g * (float)t);
      z[t] = make_float2(c0[t] * g, c1[t] * g);
    }
    for (int t = 2048 + tid; t < 4096; t += 256) z[t] = make_float2(0.f, 0.f);
  }
  fft_dif(z, tw, tid);
  float2 a0r[9], a1r[9];                     // bins k = tid + 256*j (k <= 2048)
#pragma unroll 9
  for (int j = 0; j < 9; ++j){
    int k = tid + (j << 8);
    if (k <= 2048){
      float2 zk = z[rev12(k)];
      float2 zm = z[rev12((4096 - k) & 4095)];
      a0r[j] = make_float2(0.5f*(zk.x + zm.x),  0.5f*(zk.y - zm.y));
      a1r[j] = make_float2(0.5f*(zk.y + zm.y), -0.5f*(zk.x - zm.x));
    } else {
      a0r[j] = make_float2(0.f, 0.f);
      a1r[j] = make_float2(0.f, 0.f);
    }
  }
  __syncthreads();                           // all A-spec reads done before z reuse
  // ---- per-batch convolution ----
  for (int bb = 0; bb < 4; ++bb){
    float* v0 = vt + ((size_t)bb * 3072 + 2*p) * 2048;
    float* v1 = v0 + 2048;
    for (int t = tid; t < 2048; t += 256) z[t] = make_float2(v0[t], v1[t]);
    for (int t = 2048 + tid; t < 4096; t += 256) z[t] = make_float2(0.f, 0.f);
    fft_dif(z, tw, tid);
#pragma unroll 9
    for (int j = 0; j < 9; ++j){
      int k = tid + (j << 8);
      if (k <= 2048){
        int rk  = rev12(k);
        int rmk = rev12((4096 - k) & 4095);
        float2 zk = z[rk], zm = z[rmk];
        float2 V0 = make_float2(0.5f*(zk.x + zm.x),  0.5f*(zk.y - zm.y));
        float2 V1 = make_float2(0.5f*(zk.y + zm.y), -0.5f*(zk.x - zm.x));
        float2 P0 = cmul(V0, a0r[j]);
        float2 P1 = cmul(V1, a1r[j]);
        z[rk]  = make_float2(P0.x - P1.y, -(P0.y + P1.x));
        z[rmk] = make_float2(P0.x + P1.y,   P0.y - P1.x);
      }
    }
    fft_dit(z, tw, tid);
    const float sc = 1.f / 4096.f;
    for (int t = tid; t < 2048; t += 256){
      float2 w = z[t];
      v0[t] =  w.x * sc;
      v1[t] = -w.y * sc;
    }
    __syncthreads();                         // stores done before next batch load
  }
}

// P = u .* tv written IN PLACE over u (hi/lo), 16B fully-coalesced accesses.
// Each element read+written by the same thread -> race-free. No __restrict__ on uh/ul.
__global__ __launch_bounds__(256)
void fuse_mul_inplace(ushort* uh, ushort* ul, const float* __restrict__ vt){
  __shared__ float T[64][65];                 // T[channel][t]
  int tid = threadIdx.x;
  int c0 = blockIdx.x * 64, t0 = blockIdx.y * 64;
  size_t b = blockIdx.z;
  {
    int j = tid >> 2, q = tid & 3;
    const float* src = vt + ((b * 3072 + c0 + j) * 2048 + t0 + q * 16);
#pragma unroll
    for (int f = 0; f < 4; ++f){
      float4 v = *(const float4*)(src + f * 4);
      T[j][q*16 + f*4 + 0] = v.x;
      T[j][q*16 + f*4 + 1] = v.y;
      T[j][q*16 + f*4 + 2] = v.z;
      T[j][q*16 + f*4 + 3] = v.w;
    }
  }
  __syncthreads();
  int i = tid >> 3, jq = tid & 7;             // 32 t-rows x 8 col-groups (8 ch each)
#pragma unroll
  for (int f = 0; f < 2; ++f){
    int row = i + f*32;
    size_t base = ((size_t)b * 2048 + t0 + row) * 3072 + c0 + jq*8;
    uint4 hv = *(const uint4*)&uh[base];
    uint4 lv = *(const uint4*)&ul[base];
    const uint* hp = (const uint*)&hv;
    const uint* lp = (const uint*)&lv;
    uint hr[4], lw[4];
#pragma unroll
    for (int e = 0; e < 4; ++e){
      int ch0 = jq*8 + e*2;
      float u0 = bf2f((unsigned short)(hp[e] & 0xffffu)) + bf2f((unsigned short)(lp[e] & 0xffffu));
      float u1 = bf2f((unsigned short)(hp[e] >> 16))     + bf2f((unsigned short)(lp[e] >> 16));
      float p0 = u0 * T[ch0][row];
      float p1 = u1 * T[ch0 + 1][row];
      unsigned short h0 = f2bf(p0), l0 = f2bf(p0 - bf2f(h0));
      unsigned short h1 = f2bf(p1), l1 = f2bf(p1 - bf2f(h1));
      hr[e] = (uint)h0 | ((uint)h1 << 16);
      lw[e] = (uint)l0 | ((uint)l1 << 16);
    }
    *(uint4*)&uh[base] = make_uint4(hr[0], hr[1], hr[2], hr[3]);
    *(uint4*)&ul[base] = make_uint4(lw[0], lw[1], lw[2], lw[3]);
  }
}

extern "C" void kernel_launch(void* const* d_in, const int* in_sizes, int n_in,
                              void* d_out, int out_size, void* d_ws, size_t ws_size,
                              hipStream_t stream)
{
  const float* x     = (const float*)d_in[0];
  const float* u_w   = (const float*)d_in[1];
  const float* u_b   = (const float*)d_in[2];
  const float* v_w   = (const float*)d_in[3];
  const float* v_b   = (const float*)d_in[4];
  const float* o_w   = (const float*)d_in[5];
  const float* o_b   = (const float*)d_in[6];
  const float* pos_w = (const float*)d_in[7];
  const float* pos_b = (const float*)d_in[8];
  const float* lw0   = (const float*)d_in[9];
  const float* lb0   = (const float*)d_in[10];
  const float* lw1   = (const float*)d_in[11];
  const float* lb1   = (const float*)d_in[12];
  const float* lw2   = (const float*)d_in[13];
  const float* lb2   = (const float*)d_in[14];
  const float* out_w = (const float*)d_in[15];
  const float* out_b = (const float*)d_in[16];
  float* out = (float*)d_out;

  // Footprint: 201,326,592 persistent + 17,825,792 alias = 219,152,384 B (209 MiB).
  // coefs_t lives in d_out (25.2 MB of 33.5 MB; final GEMM overwrites all of d_out).
  // Diagnostic guard: too-small ws -> clean wrong-answer (poison stays), not a crash.
  if (ws_size < 219152384) return;

  char* ws = (char*)d_ws;
  // ---- persistent region (201,326,592 B) ----
  ushort* uhi  = (ushort*)(ws);                    // 50,331,648  (u, later P hi)
  ushort* ulo  = (ushort*)(ws + 50331648);         // 50,331,648  (u, later P lo)
  float*  vt   = (float*) (ws + 100663296);        // 100,663,296 (v, later tv)
  // ---- alias region R (extent 17,825,792 B) ----
  char* R = ws + 201326592;
  // phase A (u/v GEMMs): weight-transpose slot, serialized u_w then v_w
  ushort* wT_h   = (ushort*)(R);                   // 6,291,456
  ushort* wT_l   = (ushort*)(R + 6291456);         // 6,291,456  -> end 12,582,912
  // phase B (pos-MLP; starts after v-GEMM):
  ushort* hb_h   = (ushort*)(R);                   // 2,097,152
  ushort* hb_l   = (ushort*)(R + 2097152);         // 2,097,152
  ushort* owtT_h = (ushort*)(R + 4194304);         // 3,145,728  (out_w^T hi)
  ushort* owtT_l = (ushort*)(R + 7340032);         // 3,145,728  -> end 10,485,760
  float*  h_a    = (float*) (R + 10485760);        // 4,194,304  -> end 14,680,064
  ushort* lw0T_h = (ushort*)(R + 14680064);        // 524,288 each
  ushort* lw0T_l = (ushort*)(R + 15204352);
  ushort* lw1T_h = (ushort*)(R + 15728640);
  ushort* lw1T_l = (ushort*)(R + 16252928);
  ushort* lw2T_h = (ushort*)(R + 16777216);
  ushort* lw2T_l = (ushort*)(R + 17301504);        // -> end 17,825,792
  float*  coefs_t= (float*)d_out;                  // 25,165,824 in d_out (33.5 MB)
  // phase C (after coefs GEMM; hb/owtT dead): o_w^T for the final GEMM
  ushort* owT_h  = (ushort*)(R);                   // 6,291,456
  ushort* owT_l  = (ushort*)(R + 6291456);         // 6,291,456

  dim3 blk(256);
  // ---- phase A: u/v GEMMs read x fp32 directly (ASRC=1, on-the-fly split) ----
  transpose_split<<<dim3(96, 32), blk, 0, stream>>>(u_w, wT_h, wT_l, 1024, 3072);
  gemm_mfma<1,2,1><<<dim3(24, 64), blk, 0, stream>>>(x, nullptr, nullptr, wT_h, wT_l, u_b,
                                                     nullptr, uhi, ulo, 8192, 3072, 1024);
  transpose_split<<<dim3(96, 32), blk, 0, stream>>>(v_w, wT_h, wT_l, 1024, 3072);
  gemm_mfma<1,1,1><<<dim3(24, 64), blk, 0, stream>>>(x, nullptr, nullptr, wT_h, wT_l, v_b,
                                                     vt, nullptr, nullptr, 8192, 3072, 1024);
  // ---- phase B: position MLP (split-bf16 MFMA); coefs land in d_out ----
  pos_init<<<4096, blk, 0, stream>>>(pos_w, pos_b, h_a);
  transpose_split<<<dim3(16, 16), blk, 0, stream>>>(lw0, lw0T_h, lw0T_l, 512, 512);
  transpose_split<<<dim3(16, 16), blk, 0, stream>>>(lw1, lw1T_h, lw1T_l, 512, 512);
  transpose_split<<<dim3(16, 16), blk, 0, stream>>>(lw2, lw2T_h, lw2T_l, 512, 512);
  transpose_split<<<dim3(96, 16), blk, 0, stream>>>(out_w, owtT_h, owtT_l, 512, 3072);
  srms_relu_split<<<2048, blk, 0, stream>>>(h_a, hb_h, hb_l);
  gemm_mfma<0,0,0><<<dim3(4, 16), blk, 0, stream>>>(nullptr, hb_h, hb_l, lw0T_h, lw0T_l, lb0,
                                                    h_a, nullptr, nullptr, 2048, 512, 512);
  srms_relu_split<<<2048, blk, 0, stream>>>(h_a, hb_h, hb_l);
  gemm_mfma<0,0,0><<<dim3(4, 16), blk, 0, stream>>>(nullptr, hb_h, hb_l, lw1T_h, lw1T_l, lb1,
                                                    h_a, nullptr, nullptr, 2048, 512, 512);
  srms_relu_split<<<2048, blk, 0, stream>>>(h_a, hb_h, hb_l);
  gemm_mfma<0,0,0><<<dim3(4, 16), blk, 0, stream>>>(nullptr, hb_h, hb_l, lw2T_h, lw2T_l, lb2,
                                                    h_a, nullptr, nullptr, 2048, 512, 512);
  srms_relu_split<<<2048, blk, 0, stream>>>(h_a, hb_h, hb_l);
  // coefs_t[c][t] via OUTMODE 1 (M=2048 -> bb=0); written into d_out scratch
  gemm_mfma<0,1,0><<<dim3(24, 16), blk, 0, stream>>>(nullptr, hb_h, hb_l, owtT_h, owtT_l, out_b,
                                                     coefs_t, nullptr, nullptr, 2048, 3072, 512);
  // ---- fused FFT convolution: single launch, A-spec in registers ----
  conv_fft_all<<<1536, blk, 0, stream>>>(vt, coefs_t);
  // ---- phase C: o_w^T, then P = u .* tv in place, then out = P @ o_w + o_b ----
  transpose_split<<<dim3(32, 96), blk, 0, stream>>>(o_w, owT_h, owT_l, 3072, 1024);
  fuse_mul_inplace<<<dim3(48, 32, 4), blk, 0, stream>>>(uhi, ulo, vt);
  gemm_mfma<0,0,0><<<dim3(8, 64), blk, 0, stream>>>(nullptr, uhi, ulo, owT_h, owT_l, o_b,
                                                    out, nullptr, nullptr, 8192, 1024, 3072);
}